// Round 6
// baseline (1166.579 us; speedup 1.0000x reference)
//
#include <hip/hip_runtime.h>
#include <hip/hip_fp16.h>
#include <math.h>
#include <stdio.h>

// N=50000, E=800000, IN=128, C=64, H=8, H*C=512
// Round 6 (= round 5 + compile fix): (a) GEMM LDS XOR-swizzle (kills 8-way
// bank conflicts from 64B row stride; padding impossible with
// global_load_lds), (b) GEMM epilogue splits outputs into compact KV gather
// buffer (L3-resident) + streamed QS buffer (NT stores as ushort bit pattern),
// (c) attention edge-loop unrolled x2.

using f16x8 = __attribute__((ext_vector_type(8))) _Float16;
using f32x4 = __attribute__((ext_vector_type(4))) float;

__device__ __forceinline__ void load_lds16(const void* g, void* l) {
  __builtin_amdgcn_global_load_lds((const __attribute__((address_space(1))) void*)g,
                                   (__attribute__((address_space(3))) void*)l,
                                   16, 0, 0);
}

// ---------------- CSR build ----------------
__global__ void zero_int_kernel(int* p, int n) {
  int i = blockIdx.x * blockDim.x + threadIdx.x;
  if (i < n) p[i] = 0;
}

__global__ void degree_kernel(const int* __restrict__ dst, int* __restrict__ deg, int E) {
  int e = blockIdx.x * blockDim.x + threadIdx.x;
  if (e < E) atomicAdd(&deg[dst[e]], 1);
}

__global__ __launch_bounds__(1024)
void exscan_kernel(const int* __restrict__ deg, int* __restrict__ rowptr,
                   int* __restrict__ cursor, int n) {
  __shared__ int tmp[1024];
  int tid = threadIdx.x;
  int chunk = (n + 1023) / 1024;
  int lo = tid * chunk;
  int hi = min(n, lo + chunk);
  int s = 0;
  for (int i = lo; i < hi; ++i) s += deg[i];
  int mysum = s;
  tmp[tid] = s;
  __syncthreads();
  for (int off = 1; off < 1024; off <<= 1) {
    int v = (tid >= off) ? tmp[tid - off] : 0;
    __syncthreads();
    tmp[tid] += v;
    __syncthreads();
  }
  int run = tmp[tid] - mysum;
  if (tid == 0) { rowptr[0] = 0; cursor[0] = 0; }
  for (int i = lo; i < hi; ++i) {
    run += deg[i];
    rowptr[i + 1] = run;
    cursor[i + 1] = run;
  }
}

__global__ void scatter_kernel(const int* __restrict__ src, const int* __restrict__ dst,
                               int* __restrict__ cursor, int* __restrict__ col, int E) {
  int e = blockIdx.x * blockDim.x + threadIdx.x;
  if (e < E) {
    int pos = atomicAdd(&cursor[dst[e]], 1);
    col[pos] = src[e];
  }
}

// ---------------- prep kernels ----------------
__global__ void convert_x_kernel(const float* __restrict__ x, __half* __restrict__ X16,
                                 int N, int Npad) {
  int i = blockIdx.x * 256 + threadIdx.x;
  if (i < Npad * 128) {
    int row = i >> 7;
    X16[i] = __float2half((row < N) ? x[i] : 0.f);
  }
}

__global__ void zero_pad_kernel(__half* __restrict__ H, int startElem, int numElem) {
  int i = blockIdx.x * 256 + threadIdx.x;
  if (i < numElem) H[startElem + i] = __float2half(0.f);
}

// transpose+cast: W_m fp32 [K x D] -> Wt fp16 rows [4D x K]
__global__ __launch_bounds__(256)
void transpose4_kernel(const float* __restrict__ W0, const float* __restrict__ W1,
                       const float* __restrict__ W2, const float* __restrict__ W3,
                       __half* __restrict__ Wt, int K, int D) {
  const float* W = (blockIdx.z == 0) ? W0 : (blockIdx.z == 1) ? W1
                 : (blockIdx.z == 2) ? W2 : W3;
  __shared__ float t[32][33];
  int c0 = blockIdx.x * 32, k0 = blockIdx.y * 32;
  int tx = threadIdx.x, ty = threadIdx.y;  // (32,8)
#pragma unroll
  for (int r = 0; r < 4; ++r)
    t[ty + 8 * r][tx] = W[(size_t)(k0 + ty + 8 * r) * D + c0 + tx];
  __syncthreads();
#pragma unroll
  for (int r = 0; r < 4; ++r)
    Wt[(size_t)(blockIdx.z * D + c0 + ty + 8 * r) * K + k0 + tx] =
        __float2half(t[tx][ty + 8 * r]);
}

__global__ void bias4_kernel(const float* __restrict__ b0, const float* __restrict__ b1,
                             const float* __restrict__ b2, const float* __restrict__ b3,
                             float* __restrict__ bias_all, int D) {
  int c = blockIdx.x * 256 + threadIdx.x;
  if (c < 4 * D) {
    int m = c / D;
    const float* b = (m == 0) ? b0 : (m == 1) ? b1 : (m == 2) ? b2 : b3;
    bias_all[c] = b[c - m * D];
  }
}

// ---------------- MFMA GEMM with XOR-swizzled LDS + split epilogue ----------------
// A[M x K] @ Wt^T + bias. Column gc (0..4D-1) maps: m=gc>>dshift, off=gc&(D-1);
//   m=0 (Q) -> QS[row][off]      (NT store, streamed later)
//   m=1 (K) -> KV[row][off]      (cached, gather target)
//   m=2 (V) -> KV[row][D+off]
//   m=3 (S) -> QS[row][D+off]    (NT)
// Row stride of QS/KV = 2D halves.
__global__ __launch_bounds__(256)
void gemm_mfma_kernel(const __half* __restrict__ A, int lda,
                      const __half* __restrict__ Wt,
                      const float* __restrict__ bias,
                      __half* __restrict__ QS, __half* __restrict__ KV,
                      int dshift, int K) {
  __shared__ __align__(16) __half As[128 * 32];
  __shared__ __align__(16) __half Bs[128 * 32];
  int tid = threadIdx.x;
  int wave = tid >> 6, lane = tid & 63;
  int wr = wave >> 1, wc = wave & 1;
  int m0 = blockIdx.x * 128;
  int n0 = blockIdx.y * 128;
  int lr = lane >> 2;                          // row within 16-row chunk
  int lkw = (((lane & 3) ^ (lr & 3)) << 3);    // swizzled k offset (halves)
  int quad = lane >> 4, rr = lane & 15;
  int sw = (rr & 3) << 3;                      // read-side swizzle (halves)

  f32x4 acc[4][4] = {};

  for (int kt = 0; kt < K; kt += 32) {
#pragma unroll
    for (int p = 0; p < 2; ++p) {
      int chunk = p * 64 + wave * 16;  // wave-uniform
      const __half* ga = A + (size_t)(m0 + chunk + lr) * lda + kt + lkw;
      load_lds16(ga, &As[chunk * 32]);
      const __half* gb = Wt + (size_t)(n0 + chunk + lr) * K + kt + lkw;
      load_lds16(gb, &Bs[chunk * 32]);
    }
    __syncthreads();
    f16x8 a[4], b[4];
#pragma unroll
    for (int i = 0; i < 4; ++i)
      a[i] = *(const f16x8*)&As[(wr * 64 + i * 16 + rr) * 32 + (((quad << 3) ^ sw))];
#pragma unroll
    for (int j = 0; j < 4; ++j)
      b[j] = *(const f16x8*)&Bs[(wc * 64 + j * 16 + rr) * 32 + (((quad << 3) ^ sw))];
#pragma unroll
    for (int i = 0; i < 4; ++i)
#pragma unroll
      for (int j = 0; j < 4; ++j)
        acc[i][j] = __builtin_amdgcn_mfma_f32_16x16x32_f16(a[i], b[j], acc[i][j], 0, 0, 0);
    __syncthreads();
  }

  // C/D layout: col = lane&15, row = (lane>>4)*4 + reg
  int col = lane & 15, rb = (lane >> 4) * 4;
  int D = 1 << dshift;
  int rstride = D << 1;
#pragma unroll
  for (int j = 0; j < 4; ++j) {
    int gc = n0 + wc * 64 + j * 16 + col;
    float bj = bias[gc];
    int mseg = gc >> dshift;
    int off = gc & (D - 1);
    bool toKV = (mseg == 1) || (mseg == 2);
    __half* base = toKV ? (KV + off + (mseg == 2 ? D : 0))
                        : (QS + off + (mseg == 3 ? D : 0));
#pragma unroll
    for (int i = 0; i < 4; ++i) {
#pragma unroll
      for (int r = 0; r < 4; ++r) {
        int gr = m0 + wr * 64 + i * 16 + rb + r;
        __half val = __float2half(acc[i][j][r] + bj);
        __half* ptr = base + (size_t)gr * rstride;
        if (toKV) *ptr = val;
        else __builtin_nontemporal_store(__half_as_ushort(val), (unsigned short*)ptr);
      }
    }
  }
}

// ---------------- attention H=8 C=64: one WAVE per node, edge loop x2 ----------------
// QS rows [Q(512) | S(512)], KV rows [K(512) | V(512)], stride 1024.
__global__ __launch_bounds__(256)
void attn_h8_kernel(const __half* __restrict__ QS, const __half* __restrict__ KV,
                    const int* __restrict__ rowptr, const int* __restrict__ col,
                    __half* __restrict__ Hout, int N) {
  int n = blockIdx.x * 4 + (threadIdx.x >> 6);
  if (n >= N) return;
  int lane = threadIdx.x & 63;
  size_t rbase = (size_t)n * 1024 + lane * 8;

  f16x8 qv = __builtin_nontemporal_load((const f16x8*)(QS + rbase));
  float qf[8];
#pragma unroll
  for (int j = 0; j < 8; ++j) qf[j] = (float)qv[j];

  int e0 = rowptr[n], e1 = rowptr[n + 1];
  float m = -INFINITY, l = 0.f;
  float o[8] = {};
  int i = e0;
  for (; i + 1 < e1; i += 2) {
    int s0 = col[i], s1 = col[i + 1];
    const __half* p0 = KV + (size_t)s0 * 1024 + lane * 8;
    const __half* p1 = KV + (size_t)s1 * 1024 + lane * 8;
    f16x8 k0 = *(const f16x8*)p0;
    f16x8 k1 = *(const f16x8*)p1;
    f16x8 v0 = *(const f16x8*)(p0 + 512);
    f16x8 v1 = *(const f16x8*)(p1 + 512);
    float pa = 0.f, pb = 0.f;
#pragma unroll
    for (int j = 0; j < 8; ++j) { pa += (float)k0[j] * qf[j]; pb += (float)k1[j] * qf[j]; }
    pa += __shfl_xor(pa, 1, 64); pb += __shfl_xor(pb, 1, 64);
    pa += __shfl_xor(pa, 2, 64); pb += __shfl_xor(pb, 2, 64);
    pa += __shfl_xor(pa, 4, 64); pb += __shfl_xor(pb, 4, 64);
    float a0 = pa * 0.125f, a1 = pb * 0.125f;
    float mn = fmaxf(m, fmaxf(a0, a1));
    float sc = __expf(m - mn);
    float ea = __expf(a0 - mn), eb = __expf(a1 - mn);
    l = l * sc + ea + eb;
#pragma unroll
    for (int c = 0; c < 8; ++c) o[c] = o[c] * sc + ea * (float)v0[c] + eb * (float)v1[c];
    m = mn;
  }
  if (i < e1) {
    int s0 = col[i];
    const __half* p0 = KV + (size_t)s0 * 1024 + lane * 8;
    f16x8 k0 = *(const f16x8*)p0;
    f16x8 v0 = *(const f16x8*)(p0 + 512);
    float pa = 0.f;
#pragma unroll
    for (int j = 0; j < 8; ++j) pa += (float)k0[j] * qf[j];
    pa += __shfl_xor(pa, 1, 64);
    pa += __shfl_xor(pa, 2, 64);
    pa += __shfl_xor(pa, 4, 64);
    float a0 = pa * 0.125f;
    float mn = fmaxf(m, a0);
    float sc = __expf(m - mn);
    float ea = __expf(a0 - mn);
    l = l * sc + ea;
#pragma unroll
    for (int c = 0; c < 8; ++c) o[c] = o[c] * sc + ea * (float)v0[c];
    m = mn;
  }
  float inv = 1.f / (l + 1e-16f);
  f16x8 sv = __builtin_nontemporal_load((const f16x8*)(QS + rbase + 512));
  f16x8 hv;
#pragma unroll
  for (int c = 0; c < 8; ++c) {
    float r = o[c] * inv + (float)sv[c];
    hv[c] = (_Float16)fmaxf(r, 0.f);
  }
  __builtin_nontemporal_store(hv, (f16x8*)(Hout + (size_t)n * 512 + lane * 8));
}

// ---------------- attention H=1 C=64: 8-lane group per node ----------------
// QS rows [Q(64)|S(64)], KV rows [K(64)|V(64)], stride 128. fp32 out.
__global__ __launch_bounds__(256)
void attn_h1_kernel(const __half* __restrict__ QS, const __half* __restrict__ KV,
                    const int* __restrict__ rowptr, const int* __restrict__ col,
                    float* __restrict__ out, int N) {
  int n = (blockIdx.x * 256 + threadIdx.x) >> 3;
  if (n >= N) return;
  int gl = threadIdx.x & 7;
  size_t rbase = (size_t)n * 128 + gl * 8;

  f16x8 qv = __builtin_nontemporal_load((const f16x8*)(QS + rbase));
  float qf[8];
#pragma unroll
  for (int j = 0; j < 8; ++j) qf[j] = (float)qv[j];

  int e0 = rowptr[n], e1 = rowptr[n + 1];
  float m = -INFINITY, l = 0.f;
  float o[8] = {};
  int i = e0;
  for (; i + 1 < e1; i += 2) {
    int s0 = col[i], s1 = col[i + 1];
    const __half* p0 = KV + (size_t)s0 * 128 + gl * 8;
    const __half* p1 = KV + (size_t)s1 * 128 + gl * 8;
    f16x8 k0 = *(const f16x8*)p0;
    f16x8 k1 = *(const f16x8*)p1;
    f16x8 v0 = *(const f16x8*)(p0 + 64);
    f16x8 v1 = *(const f16x8*)(p1 + 64);
    float pa = 0.f, pb = 0.f;
#pragma unroll
    for (int j = 0; j < 8; ++j) { pa += (float)k0[j] * qf[j]; pb += (float)k1[j] * qf[j]; }
    pa += __shfl_xor(pa, 1, 64); pb += __shfl_xor(pb, 1, 64);
    pa += __shfl_xor(pa, 2, 64); pb += __shfl_xor(pb, 2, 64);
    pa += __shfl_xor(pa, 4, 64); pb += __shfl_xor(pb, 4, 64);
    float a0 = pa * 0.125f, a1 = pb * 0.125f;
    float mn = fmaxf(m, fmaxf(a0, a1));
    float sc = __expf(m - mn);
    float ea = __expf(a0 - mn), eb = __expf(a1 - mn);
    l = l * sc + ea + eb;
#pragma unroll
    for (int c = 0; c < 8; ++c) o[c] = o[c] * sc + ea * (float)v0[c] + eb * (float)v1[c];
    m = mn;
  }
  if (i < e1) {
    int s0 = col[i];
    const __half* p0 = KV + (size_t)s0 * 128 + gl * 8;
    f16x8 k0 = *(const f16x8*)p0;
    f16x8 v0 = *(const f16x8*)(p0 + 64);
    float pa = 0.f;
#pragma unroll
    for (int j = 0; j < 8; ++j) pa += (float)k0[j] * qf[j];
    pa += __shfl_xor(pa, 1, 64);
    pa += __shfl_xor(pa, 2, 64);
    pa += __shfl_xor(pa, 4, 64);
    float a0 = pa * 0.125f;
    float mn = fmaxf(m, a0);
    float sc = __expf(m - mn);
    float ea = __expf(a0 - mn);
    l = l * sc + ea;
#pragma unroll
    for (int c = 0; c < 8; ++c) o[c] = o[c] * sc + ea * (float)v0[c];
    m = mn;
  }
  float inv = 1.f / (l + 1e-16f);
  f16x8 sv = __builtin_nontemporal_load((const f16x8*)(QS + rbase + 64));
  f32x4 r0, r1;
#pragma unroll
  for (int c = 0; c < 4; ++c) r0[c] = o[c] * inv + (float)sv[c];
#pragma unroll
  for (int c = 0; c < 4; ++c) r1[c] = o[c + 4] * inv + (float)sv[c + 4];
  float* op = out + (size_t)n * 64 + gl * 8;
  *(f32x4*)op = r0;
  *(f32x4*)(op + 4) = r1;
}

extern "C" void kernel_launch(void* const* d_in, const int* in_sizes, int n_in,
                              void* d_out, int out_size, void* d_ws, size_t ws_size,
                              hipStream_t stream) {
  const float* x = (const float*)d_in[0];
  const int* ei = (const int*)d_in[1];
  const int N = in_sizes[0] / 128;
  const int E = in_sizes[1] / 2;
  const int Npad = ((N + 127) / 128) * 128;
  const int* srcp = ei;
  const int* dstp = ei + E;

  const float* Wq0 = (const float*)d_in[2];  const float* bq0 = (const float*)d_in[3];
  const float* Wk0 = (const float*)d_in[4];  const float* bk0 = (const float*)d_in[5];
  const float* Wv0 = (const float*)d_in[6];  const float* bv0 = (const float*)d_in[7];
  const float* Ws0 = (const float*)d_in[8];  const float* bs0 = (const float*)d_in[9];
  const float* Wq1 = (const float*)d_in[10]; const float* bq1 = (const float*)d_in[11];
  const float* Wk1 = (const float*)d_in[12]; const float* bk1 = (const float*)d_in[13];
  const float* Wv1 = (const float*)d_in[14]; const float* bv1 = (const float*)d_in[15];
  const float* Ws1 = (const float*)d_in[16]; const float* bs1 = (const float*)d_in[17];
  const float* Wq2 = (const float*)d_in[18]; const float* bq2 = (const float*)d_in[19];
  const float* Wk2 = (const float*)d_in[20]; const float* bk2 = (const float*)d_in[21];
  const float* Wv2 = (const float*)d_in[22]; const float* bv2 = (const float*)d_in[23];
  const float* Ws2 = (const float*)d_in[24]; const float* bs2 = (const float*)d_in[25];

  // ---- workspace layout (~262.2 MB) ----
  char* p = (char*)d_ws;
  __half* QS = (__half*)p;               p += (size_t)Npad * 1024 * 2;  // 102.5 MB
  __half* KV = (__half*)p;               p += (size_t)Npad * 1024 * 2;  // 102.5 MB
  __half* H  = (__half*)p;               p += (size_t)Npad * 512 * 2;   // 51.25 MB
  __half* X16 = H;  // aliases H; dead before H is first written
  __half* Wt = (__half*)p;               p += (size_t)2048 * 512 * 2;   // 2 MB
  float* bias_all = (float*)p;           p += 2048 * 4;
  int* deg    = (int*)p;                 p += (size_t)N * 4;
  int* rowptr = (int*)p;                 p += (size_t)(N + 1) * 4;
  int* cursor = (int*)p;                 p += (size_t)(N + 1) * 4;
  int* colv   = (int*)p;                 p += (size_t)E * 4;
  size_t need = p - (char*)d_ws;
  if (ws_size < need) {
    fprintf(stderr, "kernel_launch: ws_size=%zu < need=%zu — aborting cleanly\n",
            ws_size, need);
    return;
  }

  // ---- prep ----
  convert_x_kernel<<<(Npad * 128 + 255) / 256, 256, 0, stream>>>(x, X16, N, Npad);
  zero_pad_kernel<<<((Npad - N) * 512 + 255) / 256, 256, 0, stream>>>(
      H, N * 512, (Npad - N) * 512);

  // ---- CSR build ----
  zero_int_kernel<<<(N + 255) / 256, 256, 0, stream>>>(deg, N);
  degree_kernel<<<(E + 255) / 256, 256, 0, stream>>>(dstp, deg, E);
  exscan_kernel<<<1, 1024, 0, stream>>>(deg, rowptr, cursor, N);
  scatter_kernel<<<(E + 255) / 256, 256, 0, stream>>>(srcp, dstp, cursor, colv, E);

  const int mtiles = Npad / 128;

  // ---- layer 0: K=128, D=512 ----
  transpose4_kernel<<<dim3(512 / 32, 128 / 32, 4), dim3(32, 8), 0, stream>>>(
      Wq0, Wk0, Wv0, Ws0, Wt, 128, 512);
  bias4_kernel<<<(2048 + 255) / 256, 256, 0, stream>>>(bq0, bk0, bv0, bs0, bias_all, 512);
  gemm_mfma_kernel<<<dim3(mtiles, 2048 / 128), 256, 0, stream>>>(
      X16, 128, Wt, bias_all, QS, KV, 9, 128);
  attn_h8_kernel<<<(N + 3) / 4, 256, 0, stream>>>(QS, KV, rowptr, colv, H, N);

  // ---- layer 1: K=512, D=512 ----
  transpose4_kernel<<<dim3(512 / 32, 512 / 32, 4), dim3(32, 8), 0, stream>>>(
      Wq1, Wk1, Wv1, Ws1, Wt, 512, 512);
  bias4_kernel<<<(2048 + 255) / 256, 256, 0, stream>>>(bq1, bk1, bv1, bs1, bias_all, 512);
  gemm_mfma_kernel<<<dim3(mtiles, 2048 / 128), 256, 0, stream>>>(
      H, 512, Wt, bias_all, QS, KV, 9, 512);
  attn_h8_kernel<<<(N + 3) / 4, 256, 0, stream>>>(QS, KV, rowptr, colv, H, N);

  // ---- layer 2: K=512, D=64 ----
  transpose4_kernel<<<dim3(64 / 32, 512 / 32, 4), dim3(32, 8), 0, stream>>>(
      Wq2, Wk2, Wv2, Ws2, Wt, 512, 64);
  bias4_kernel<<<1, 256, 0, stream>>>(bq2, bk2, bv2, bs2, bias_all, 64);
  gemm_mfma_kernel<<<dim3(mtiles, 256 / 128), 256, 0, stream>>>(
      H, 512, Wt, bias_all, QS, KV, 6, 512);
  attn_h1_kernel<<<(N + 31) / 32, 256, 0, stream>>>(QS, KV, rowptr, colv,
                                                    (float*)d_out, N);
}

// Round 7
// 1156.189 us; speedup vs baseline: 1.0090x; 1.0090x over previous
//
#include <hip/hip_runtime.h>
#include <hip/hip_fp16.h>
#include <math.h>
#include <stdio.h>

// N=50000, E=800000, IN=128, C=64, H=8, H*C=512
// Round 7: attention edge loop software-pipelined 2 pairs deep (prefetch
// K/V rows for edges i+2,i+3 while processing i,i+1) — attacks the exposed
// L2-miss latency (VALUBusy 32%, occ 61%). GEMM epilogue NT stores reverted
// (round-6 regression suspect). LDS XOR swizzle kept.

using f16x8 = __attribute__((ext_vector_type(8))) _Float16;
using f32x4 = __attribute__((ext_vector_type(4))) float;

__device__ __forceinline__ void load_lds16(const void* g, void* l) {
  __builtin_amdgcn_global_load_lds((const __attribute__((address_space(1))) void*)g,
                                   (__attribute__((address_space(3))) void*)l,
                                   16, 0, 0);
}

// ---------------- CSR build ----------------
__global__ void zero_int_kernel(int* p, int n) {
  int i = blockIdx.x * blockDim.x + threadIdx.x;
  if (i < n) p[i] = 0;
}

__global__ void degree_kernel(const int* __restrict__ dst, int* __restrict__ deg, int E) {
  int e = blockIdx.x * blockDim.x + threadIdx.x;
  if (e < E) atomicAdd(&deg[dst[e]], 1);
}

__global__ __launch_bounds__(1024)
void exscan_kernel(const int* __restrict__ deg, int* __restrict__ rowptr,
                   int* __restrict__ cursor, int n) {
  __shared__ int tmp[1024];
  int tid = threadIdx.x;
  int chunk = (n + 1023) / 1024;
  int lo = tid * chunk;
  int hi = min(n, lo + chunk);
  int s = 0;
  for (int i = lo; i < hi; ++i) s += deg[i];
  int mysum = s;
  tmp[tid] = s;
  __syncthreads();
  for (int off = 1; off < 1024; off <<= 1) {
    int v = (tid >= off) ? tmp[tid - off] : 0;
    __syncthreads();
    tmp[tid] += v;
    __syncthreads();
  }
  int run = tmp[tid] - mysum;
  if (tid == 0) { rowptr[0] = 0; cursor[0] = 0; }
  for (int i = lo; i < hi; ++i) {
    run += deg[i];
    rowptr[i + 1] = run;
    cursor[i + 1] = run;
  }
}

__global__ void scatter_kernel(const int* __restrict__ src, const int* __restrict__ dst,
                               int* __restrict__ cursor, int* __restrict__ col, int E) {
  int e = blockIdx.x * blockDim.x + threadIdx.x;
  if (e < E) {
    int pos = atomicAdd(&cursor[dst[e]], 1);
    col[pos] = src[e];
  }
}

// ---------------- prep kernels ----------------
__global__ void convert_x_kernel(const float* __restrict__ x, __half* __restrict__ X16,
                                 int N, int Npad) {
  int i = blockIdx.x * 256 + threadIdx.x;
  if (i < Npad * 128) {
    int row = i >> 7;
    X16[i] = __float2half((row < N) ? x[i] : 0.f);
  }
}

__global__ void zero_pad_kernel(__half* __restrict__ H, int startElem, int numElem) {
  int i = blockIdx.x * 256 + threadIdx.x;
  if (i < numElem) H[startElem + i] = __float2half(0.f);
}

// transpose+cast: W_m fp32 [K x D] -> Wt fp16 rows [4D x K]
__global__ __launch_bounds__(256)
void transpose4_kernel(const float* __restrict__ W0, const float* __restrict__ W1,
                       const float* __restrict__ W2, const float* __restrict__ W3,
                       __half* __restrict__ Wt, int K, int D) {
  const float* W = (blockIdx.z == 0) ? W0 : (blockIdx.z == 1) ? W1
                 : (blockIdx.z == 2) ? W2 : W3;
  __shared__ float t[32][33];
  int c0 = blockIdx.x * 32, k0 = blockIdx.y * 32;
  int tx = threadIdx.x, ty = threadIdx.y;  // (32,8)
#pragma unroll
  for (int r = 0; r < 4; ++r)
    t[ty + 8 * r][tx] = W[(size_t)(k0 + ty + 8 * r) * D + c0 + tx];
  __syncthreads();
#pragma unroll
  for (int r = 0; r < 4; ++r)
    Wt[(size_t)(blockIdx.z * D + c0 + ty + 8 * r) * K + k0 + tx] =
        __float2half(t[tx][ty + 8 * r]);
}

__global__ void bias4_kernel(const float* __restrict__ b0, const float* __restrict__ b1,
                             const float* __restrict__ b2, const float* __restrict__ b3,
                             float* __restrict__ bias_all, int D) {
  int c = blockIdx.x * 256 + threadIdx.x;
  if (c < 4 * D) {
    int m = c / D;
    const float* b = (m == 0) ? b0 : (m == 1) ? b1 : (m == 2) ? b2 : b3;
    bias_all[c] = b[c - m * D];
  }
}

// ---------------- MFMA GEMM with XOR-swizzled LDS + split epilogue ----------------
// A[M x K] @ Wt^T + bias. Column gc: m=gc>>dshift, off=gc&(D-1);
//   m=0 (Q) -> QS[row][off]; m=1 (K) -> KV[row][off];
//   m=2 (V) -> KV[row][D+off]; m=3 (S) -> QS[row][D+off]. Row stride 2D.
__global__ __launch_bounds__(256)
void gemm_mfma_kernel(const __half* __restrict__ A, int lda,
                      const __half* __restrict__ Wt,
                      const float* __restrict__ bias,
                      __half* __restrict__ QS, __half* __restrict__ KV,
                      int dshift, int K) {
  __shared__ __align__(16) __half As[128 * 32];
  __shared__ __align__(16) __half Bs[128 * 32];
  int tid = threadIdx.x;
  int wave = tid >> 6, lane = tid & 63;
  int wr = wave >> 1, wc = wave & 1;
  int m0 = blockIdx.x * 128;
  int n0 = blockIdx.y * 128;
  int lr = lane >> 2;                          // row within 16-row chunk
  int lkw = (((lane & 3) ^ (lr & 3)) << 3);    // swizzled k offset (halves)
  int quad = lane >> 4, rr = lane & 15;
  int sw = (rr & 3) << 3;                      // read-side swizzle (halves)

  f32x4 acc[4][4] = {};

  for (int kt = 0; kt < K; kt += 32) {
#pragma unroll
    for (int p = 0; p < 2; ++p) {
      int chunk = p * 64 + wave * 16;  // wave-uniform
      const __half* ga = A + (size_t)(m0 + chunk + lr) * lda + kt + lkw;
      load_lds16(ga, &As[chunk * 32]);
      const __half* gb = Wt + (size_t)(n0 + chunk + lr) * K + kt + lkw;
      load_lds16(gb, &Bs[chunk * 32]);
    }
    __syncthreads();
    f16x8 a[4], b[4];
#pragma unroll
    for (int i = 0; i < 4; ++i)
      a[i] = *(const f16x8*)&As[(wr * 64 + i * 16 + rr) * 32 + (((quad << 3) ^ sw))];
#pragma unroll
    for (int j = 0; j < 4; ++j)
      b[j] = *(const f16x8*)&Bs[(wc * 64 + j * 16 + rr) * 32 + (((quad << 3) ^ sw))];
#pragma unroll
    for (int i = 0; i < 4; ++i)
#pragma unroll
      for (int j = 0; j < 4; ++j)
        acc[i][j] = __builtin_amdgcn_mfma_f32_16x16x32_f16(a[i], b[j], acc[i][j], 0, 0, 0);
    __syncthreads();
  }

  // C/D layout: col = lane&15, row = (lane>>4)*4 + reg
  int col = lane & 15, rb = (lane >> 4) * 4;
  int D = 1 << dshift;
  int rstride = D << 1;
#pragma unroll
  for (int j = 0; j < 4; ++j) {
    int gc = n0 + wc * 64 + j * 16 + col;
    float bj = bias[gc];
    int mseg = gc >> dshift;
    int off = gc & (D - 1);
    bool toKV = (mseg == 1) || (mseg == 2);
    __half* base = toKV ? (KV + off + (mseg == 2 ? D : 0))
                        : (QS + off + (mseg == 3 ? D : 0));
#pragma unroll
    for (int i = 0; i < 4; ++i) {
#pragma unroll
      for (int r = 0; r < 4; ++r) {
        int gr = m0 + wr * 64 + i * 16 + rb + r;
        base[(size_t)gr * rstride] = __float2half(acc[i][j][r] + bj);
      }
    }
  }
}

// ---------------- attention H=8 C=64: one WAVE per node, 2-pair pipeline ----------------
// QS rows [Q(512)|S(512)], KV rows [K(512)|V(512)], stride 1024.
__global__ __launch_bounds__(256)
void attn_h8_kernel(const __half* __restrict__ QS, const __half* __restrict__ KV,
                    const int* __restrict__ rowptr, const int* __restrict__ col,
                    __half* __restrict__ Hout, int N) {
  int n = blockIdx.x * 4 + (threadIdx.x >> 6);
  if (n >= N) return;
  int lane = threadIdx.x & 63;
  size_t rbase = (size_t)n * 1024 + lane * 8;

  f16x8 qv = __builtin_nontemporal_load((const f16x8*)(QS + rbase));
  float qf[8];
#pragma unroll
  for (int j = 0; j < 8; ++j) qf[j] = (float)qv[j];

  int e0 = rowptr[n], e1 = rowptr[n + 1];
  float m = -INFINITY, l = 0.f;
  float o[8] = {};

  // stage registers: pair (a,b) in flight
  f16x8 ka = {}, va = {}, kb = {}, vb = {};
  int i = e0;
  if (i < e1) {
    const __half* p = KV + (size_t)col[i] * 1024 + lane * 8;
    ka = *(const f16x8*)p; va = *(const f16x8*)(p + 512);
  }
  if (i + 1 < e1) {
    const __half* p = KV + (size_t)col[i + 1] * 1024 + lane * 8;
    kb = *(const f16x8*)p; vb = *(const f16x8*)(p + 512);
  }

  while (i < e1) {
    int rem = e1 - i;
    // prefetch pair i+2 / i+3 (in flight while we process the current pair)
    f16x8 kc = {}, vc = {}, kd = {}, vd = {};
    if (rem > 2) {
      const __half* p = KV + (size_t)col[i + 2] * 1024 + lane * 8;
      kc = *(const f16x8*)p; vc = *(const f16x8*)(p + 512);
    }
    if (rem > 3) {
      const __half* p = KV + (size_t)col[i + 3] * 1024 + lane * 8;
      kd = *(const f16x8*)p; vd = *(const f16x8*)(p + 512);
    }
    // process current pair
    float pa = 0.f, pb = 0.f;
#pragma unroll
    for (int j = 0; j < 8; ++j) { pa += (float)ka[j] * qf[j]; pb += (float)kb[j] * qf[j]; }
    pa += __shfl_xor(pa, 1, 64); pb += __shfl_xor(pb, 1, 64);
    pa += __shfl_xor(pa, 2, 64); pb += __shfl_xor(pb, 2, 64);
    pa += __shfl_xor(pa, 4, 64); pb += __shfl_xor(pb, 4, 64);
    float a0 = pa * 0.125f;
    if (rem > 1) {
      float a1 = pb * 0.125f;
      float mn = fmaxf(m, fmaxf(a0, a1));
      float sc = __expf(m - mn);
      float ea = __expf(a0 - mn), eb = __expf(a1 - mn);
      l = l * sc + ea + eb;
#pragma unroll
      for (int c = 0; c < 8; ++c)
        o[c] = o[c] * sc + ea * (float)va[c] + eb * (float)vb[c];
      m = mn;
    } else {
      float mn = fmaxf(m, a0);
      float sc = __expf(m - mn);
      float ea = __expf(a0 - mn);
      l = l * sc + ea;
#pragma unroll
      for (int c = 0; c < 8; ++c) o[c] = o[c] * sc + ea * (float)va[c];
      m = mn;
    }
    ka = kc; va = vc; kb = kd; vb = vd;
    i += 2;
  }

  float inv = 1.f / (l + 1e-16f);
  f16x8 sv = __builtin_nontemporal_load((const f16x8*)(QS + rbase + 512));
  f16x8 hv;
#pragma unroll
  for (int c = 0; c < 8; ++c) {
    float r = o[c] * inv + (float)sv[c];
    hv[c] = (_Float16)fmaxf(r, 0.f);
  }
  __builtin_nontemporal_store(hv, (f16x8*)(Hout + (size_t)n * 512 + lane * 8));
}

// ---------------- attention H=1 C=64: 8-lane group per node, pipelined ----------------
// QS rows [Q(64)|S(64)], KV rows [K(64)|V(64)], stride 128. fp32 out.
__global__ __launch_bounds__(256)
void attn_h1_kernel(const __half* __restrict__ QS, const __half* __restrict__ KV,
                    const int* __restrict__ rowptr, const int* __restrict__ col,
                    float* __restrict__ out, int N) {
  int n = (blockIdx.x * 256 + threadIdx.x) >> 3;
  if (n >= N) return;
  int gl = threadIdx.x & 7;
  size_t rbase = (size_t)n * 128 + gl * 8;

  f16x8 qv = __builtin_nontemporal_load((const f16x8*)(QS + rbase));
  float qf[8];
#pragma unroll
  for (int j = 0; j < 8; ++j) qf[j] = (float)qv[j];

  int e0 = rowptr[n], e1 = rowptr[n + 1];
  float m = -INFINITY, l = 0.f;
  float o[8] = {};

  f16x8 ka = {}, va = {}, kb = {}, vb = {};
  int i = e0;
  if (i < e1) {
    const __half* p = KV + (size_t)col[i] * 128 + gl * 8;
    ka = *(const f16x8*)p; va = *(const f16x8*)(p + 64);
  }
  if (i + 1 < e1) {
    const __half* p = KV + (size_t)col[i + 1] * 128 + gl * 8;
    kb = *(const f16x8*)p; vb = *(const f16x8*)(p + 64);
  }

  while (i < e1) {
    int rem = e1 - i;
    f16x8 kc = {}, vc = {}, kd = {}, vd = {};
    if (rem > 2) {
      const __half* p = KV + (size_t)col[i + 2] * 128 + gl * 8;
      kc = *(const f16x8*)p; vc = *(const f16x8*)(p + 64);
    }
    if (rem > 3) {
      const __half* p = KV + (size_t)col[i + 3] * 128 + gl * 8;
      kd = *(const f16x8*)p; vd = *(const f16x8*)(p + 64);
    }
    float pa = 0.f, pb = 0.f;
#pragma unroll
    for (int j = 0; j < 8; ++j) { pa += (float)ka[j] * qf[j]; pb += (float)kb[j] * qf[j]; }
    pa += __shfl_xor(pa, 1, 64); pb += __shfl_xor(pb, 1, 64);
    pa += __shfl_xor(pa, 2, 64); pb += __shfl_xor(pb, 2, 64);
    pa += __shfl_xor(pa, 4, 64); pb += __shfl_xor(pb, 4, 64);
    float a0 = pa * 0.125f;
    if (rem > 1) {
      float a1 = pb * 0.125f;
      float mn = fmaxf(m, fmaxf(a0, a1));
      float sc = __expf(m - mn);
      float ea = __expf(a0 - mn), eb = __expf(a1 - mn);
      l = l * sc + ea + eb;
#pragma unroll
      for (int c = 0; c < 8; ++c)
        o[c] = o[c] * sc + ea * (float)va[c] + eb * (float)vb[c];
      m = mn;
    } else {
      float mn = fmaxf(m, a0);
      float sc = __expf(m - mn);
      float ea = __expf(a0 - mn);
      l = l * sc + ea;
#pragma unroll
      for (int c = 0; c < 8; ++c) o[c] = o[c] * sc + ea * (float)va[c];
      m = mn;
    }
    ka = kc; va = vc; kb = kd; vb = vd;
    i += 2;
  }

  float inv = 1.f / (l + 1e-16f);
  f16x8 sv = __builtin_nontemporal_load((const f16x8*)(QS + rbase + 64));
  f32x4 r0, r1;
#pragma unroll
  for (int c = 0; c < 4; ++c) r0[c] = o[c] * inv + (float)sv[c];
#pragma unroll
  for (int c = 0; c < 4; ++c) r1[c] = o[c + 4] * inv + (float)sv[c + 4];
  float* op = out + (size_t)n * 64 + gl * 8;
  *(f32x4*)op = r0;
  *(f32x4*)(op + 4) = r1;
}

extern "C" void kernel_launch(void* const* d_in, const int* in_sizes, int n_in,
                              void* d_out, int out_size, void* d_ws, size_t ws_size,
                              hipStream_t stream) {
  const float* x = (const float*)d_in[0];
  const int* ei = (const int*)d_in[1];
  const int N = in_sizes[0] / 128;
  const int E = in_sizes[1] / 2;
  const int Npad = ((N + 127) / 128) * 128;
  const int* srcp = ei;
  const int* dstp = ei + E;

  const float* Wq0 = (const float*)d_in[2];  const float* bq0 = (const float*)d_in[3];
  const float* Wk0 = (const float*)d_in[4];  const float* bk0 = (const float*)d_in[5];
  const float* Wv0 = (const float*)d_in[6];  const float* bv0 = (const float*)d_in[7];
  const float* Ws0 = (const float*)d_in[8];  const float* bs0 = (const float*)d_in[9];
  const float* Wq1 = (const float*)d_in[10]; const float* bq1 = (const float*)d_in[11];
  const float* Wk1 = (const float*)d_in[12]; const float* bk1 = (const float*)d_in[13];
  const float* Wv1 = (const float*)d_in[14]; const float* bv1 = (const float*)d_in[15];
  const float* Ws1 = (const float*)d_in[16]; const float* bs1 = (const float*)d_in[17];
  const float* Wq2 = (const float*)d_in[18]; const float* bq2 = (const float*)d_in[19];
  const float* Wk2 = (const float*)d_in[20]; const float* bk2 = (const float*)d_in[21];
  const float* Wv2 = (const float*)d_in[22]; const float* bv2 = (const float*)d_in[23];
  const float* Ws2 = (const float*)d_in[24]; const float* bs2 = (const float*)d_in[25];

  // ---- workspace layout (~262.2 MB) ----
  char* p = (char*)d_ws;
  __half* QS = (__half*)p;               p += (size_t)Npad * 1024 * 2;  // 102.5 MB
  __half* KV = (__half*)p;               p += (size_t)Npad * 1024 * 2;  // 102.5 MB
  __half* H  = (__half*)p;               p += (size_t)Npad * 512 * 2;   // 51.25 MB
  __half* X16 = H;  // aliases H; dead before H is first written
  __half* Wt = (__half*)p;               p += (size_t)2048 * 512 * 2;   // 2 MB
  float* bias_all = (float*)p;           p += 2048 * 4;
  int* deg    = (int*)p;                 p += (size_t)N * 4;
  int* rowptr = (int*)p;                 p += (size_t)(N + 1) * 4;
  int* cursor = (int*)p;                 p += (size_t)(N + 1) * 4;
  int* colv   = (int*)p;                 p += (size_t)E * 4;
  size_t need = p - (char*)d_ws;
  if (ws_size < need) {
    fprintf(stderr, "kernel_launch: ws_size=%zu < need=%zu — aborting cleanly\n",
            ws_size, need);
    return;
  }

  // ---- prep ----
  convert_x_kernel<<<(Npad * 128 + 255) / 256, 256, 0, stream>>>(x, X16, N, Npad);
  zero_pad_kernel<<<((Npad - N) * 512 + 255) / 256, 256, 0, stream>>>(
      H, N * 512, (Npad - N) * 512);

  // ---- CSR build ----
  zero_int_kernel<<<(N + 255) / 256, 256, 0, stream>>>(deg, N);
  degree_kernel<<<(E + 255) / 256, 256, 0, stream>>>(dstp, deg, E);
  exscan_kernel<<<1, 1024, 0, stream>>>(deg, rowptr, cursor, N);
  scatter_kernel<<<(E + 255) / 256, 256, 0, stream>>>(srcp, dstp, cursor, colv, E);

  const int mtiles = Npad / 128;

  // ---- layer 0: K=128, D=512 ----
  transpose4_kernel<<<dim3(512 / 32, 128 / 32, 4), dim3(32, 8), 0, stream>>>(
      Wq0, Wk0, Wv0, Ws0, Wt, 128, 512);
  bias4_kernel<<<(2048 + 255) / 256, 256, 0, stream>>>(bq0, bk0, bv0, bs0, bias_all, 512);
  gemm_mfma_kernel<<<dim3(mtiles, 2048 / 128), 256, 0, stream>>>(
      X16, 128, Wt, bias_all, QS, KV, 9, 128);
  attn_h8_kernel<<<(N + 3) / 4, 256, 0, stream>>>(QS, KV, rowptr, colv, H, N);

  // ---- layer 1: K=512, D=512 ----
  transpose4_kernel<<<dim3(512 / 32, 512 / 32, 4), dim3(32, 8), 0, stream>>>(
      Wq1, Wk1, Wv1, Ws1, Wt, 512, 512);
  bias4_kernel<<<(2048 + 255) / 256, 256, 0, stream>>>(bq1, bk1, bv1, bs1, bias_all, 512);
  gemm_mfma_kernel<<<dim3(mtiles, 2048 / 128), 256, 0, stream>>>(
      H, 512, Wt, bias_all, QS, KV, 9, 512);
  attn_h8_kernel<<<(N + 3) / 4, 256, 0, stream>>>(QS, KV, rowptr, colv, H, N);

  // ---- layer 2: K=512, D=64 ----
  transpose4_kernel<<<dim3(64 / 32, 512 / 32, 4), dim3(32, 8), 0, stream>>>(
      Wq2, Wk2, Wv2, Ws2, Wt, 512, 64);
  bias4_kernel<<<1, 256, 0, stream>>>(bq2, bk2, bv2, bs2, bias_all, 64);
  gemm_mfma_kernel<<<dim3(mtiles, 256 / 128), 256, 0, stream>>>(
      H, 512, Wt, bias_all, QS, KV, 6, 512);
  attn_h1_kernel<<<(N + 31) / 32, 256, 0, stream>>>(QS, KV, rowptr, colv,
                                                    (float*)d_out, N);
}

// Round 8
// 1115.197 us; speedup vs baseline: 1.0461x; 1.0368x over previous
//
#include <hip/hip_runtime.h>
#include <hip/hip_fp16.h>
#include <math.h>
#include <stdio.h>

// N=50000, E=800000, IN=128, C=64, H=8, H*C=512
// Round 8: GEMM BK=64 (halve barrier drains; K is short so barriers are a
// big fraction), merged transpose/bias prep launches, vectorized convert_x.
// Attention unchanged (established as bandwidth-bound at ~3.78 TB/s fetch).

using f16x8 = __attribute__((ext_vector_type(8))) _Float16;
using f32x4 = __attribute__((ext_vector_type(4))) float;

__device__ __forceinline__ void load_lds16(const void* g, void* l) {
  __builtin_amdgcn_global_load_lds((const __attribute__((address_space(1))) void*)g,
                                   (__attribute__((address_space(3))) void*)l,
                                   16, 0, 0);
}

// ---------------- CSR build ----------------
__global__ void zero_int_kernel(int* p, int n) {
  int i = blockIdx.x * blockDim.x + threadIdx.x;
  if (i < n) p[i] = 0;
}

__global__ void degree_kernel(const int* __restrict__ dst, int* __restrict__ deg, int E) {
  int e = blockIdx.x * blockDim.x + threadIdx.x;
  if (e < E) atomicAdd(&deg[dst[e]], 1);
}

__global__ __launch_bounds__(1024)
void exscan_kernel(const int* __restrict__ deg, int* __restrict__ rowptr,
                   int* __restrict__ cursor, int n) {
  __shared__ int tmp[1024];
  int tid = threadIdx.x;
  int chunk = (n + 1023) / 1024;
  int lo = tid * chunk;
  int hi = min(n, lo + chunk);
  int s = 0;
  for (int i = lo; i < hi; ++i) s += deg[i];
  int mysum = s;
  tmp[tid] = s;
  __syncthreads();
  for (int off = 1; off < 1024; off <<= 1) {
    int v = (tid >= off) ? tmp[tid - off] : 0;
    __syncthreads();
    tmp[tid] += v;
    __syncthreads();
  }
  int run = tmp[tid] - mysum;
  if (tid == 0) { rowptr[0] = 0; cursor[0] = 0; }
  for (int i = lo; i < hi; ++i) {
    run += deg[i];
    rowptr[i + 1] = run;
    cursor[i + 1] = run;
  }
}

__global__ void scatter_kernel(const int* __restrict__ src, const int* __restrict__ dst,
                               int* __restrict__ cursor, int* __restrict__ col, int E) {
  int e = blockIdx.x * blockDim.x + threadIdx.x;
  if (e < E) {
    int pos = atomicAdd(&cursor[dst[e]], 1);
    col[pos] = src[e];
  }
}

// ---------------- prep kernels ----------------
// vectorized: 8 fp32 in -> 8 fp16 out per thread
__global__ void convert_x_kernel(const float* __restrict__ x, __half* __restrict__ X16,
                                 int N, int Npad) {
  int i = (blockIdx.x * 256 + threadIdx.x) * 8;
  if (i >= Npad * 128) return;
  int row = i >> 7;
  f16x8 hv;
  if (row < N) {
    const float* xp = x + i;
#pragma unroll
    for (int j = 0; j < 8; ++j) hv[j] = (_Float16)xp[j];
  } else {
#pragma unroll
    for (int j = 0; j < 8; ++j) hv[j] = (_Float16)0.f;
  }
  *(f16x8*)(X16 + i) = hv;
}

__global__ void zero_pad_kernel(__half* __restrict__ H, int startElem, int numElem) {
  int i = blockIdx.x * 256 + threadIdx.x;
  if (i < numElem) H[startElem + i] = __float2half(0.f);
}

// ALL 12 weight transposes in one launch. z = layer*4 + m.
// Wt arena: l0 @0 (2048 rows x 128), l1 @262144 (2048 x 512), l2 @1310720 (256 x 512).
__global__ __launch_bounds__(256)
void transpose_all_kernel(
    const float* __restrict__ Wq0, const float* __restrict__ Wk0,
    const float* __restrict__ Wv0, const float* __restrict__ Ws0,
    const float* __restrict__ Wq1, const float* __restrict__ Wk1,
    const float* __restrict__ Wv1, const float* __restrict__ Ws1,
    const float* __restrict__ Wq2, const float* __restrict__ Wk2,
    const float* __restrict__ Wv2, const float* __restrict__ Ws2,
    __half* __restrict__ Wt) {
  int z = blockIdx.z;
  int layer = z >> 2, m = z & 3;
  int K = (layer == 0) ? 128 : 512;
  int D = (layer == 2) ? 64 : 512;
  int c0 = blockIdx.x * 32, k0 = blockIdx.y * 32;
  if (c0 >= D || k0 >= K) return;
  const float* W;
  switch (z) {
    case 0: W = Wq0; break; case 1: W = Wk0; break;
    case 2: W = Wv0; break; case 3: W = Ws0; break;
    case 4: W = Wq1; break; case 5: W = Wk1; break;
    case 6: W = Wv1; break; case 7: W = Ws1; break;
    case 8: W = Wq2; break; case 9: W = Wk2; break;
    case 10: W = Wv2; break; default: W = Ws2; break;
  }
  __half* dstBase = Wt + ((layer == 0) ? 0 : (layer == 1) ? 262144 : 1310720);
  __shared__ float t[32][33];
  int tx = threadIdx.x & 31, ty = threadIdx.x >> 5;  // (32,8)
#pragma unroll
  for (int r = 0; r < 4; ++r)
    t[ty + 8 * r][tx] = W[(size_t)(k0 + ty + 8 * r) * D + c0 + tx];
  __syncthreads();
#pragma unroll
  for (int r = 0; r < 4; ++r)
    dstBase[(size_t)(m * D + c0 + ty + 8 * r) * K + k0 + tx] =
        __float2half(t[tx][ty + 8 * r]);
}

// ALL 12 biases in one launch. block = matrix (z = layer*4+m).
// bias arena: l0 @0 (2048), l1 @2048 (2048), l2 @4096 (256).
__global__ void bias_all_kernel(
    const float* __restrict__ b0, const float* __restrict__ b1,
    const float* __restrict__ b2, const float* __restrict__ b3,
    const float* __restrict__ b4, const float* __restrict__ b5,
    const float* __restrict__ b6, const float* __restrict__ b7,
    const float* __restrict__ b8, const float* __restrict__ b9,
    const float* __restrict__ b10, const float* __restrict__ b11,
    float* __restrict__ bias_arena) {
  int z = blockIdx.x;
  int layer = z >> 2, m = z & 3;
  int D = (layer == 2) ? 64 : 512;
  const float* b;
  switch (z) {
    case 0: b = b0; break; case 1: b = b1; break;
    case 2: b = b2; break; case 3: b = b3; break;
    case 4: b = b4; break; case 5: b = b5; break;
    case 6: b = b6; break; case 7: b = b7; break;
    case 8: b = b8; break; case 9: b = b9; break;
    case 10: b = b10; break; default: b = b11; break;
  }
  float* dst = bias_arena + ((layer == 0) ? 0 : (layer == 1) ? 2048 : 4096) + m * D;
  for (int c = threadIdx.x; c < D; c += 256) dst[c] = b[c];
}

// ---------------- MFMA GEMM, BK=64, XOR-swizzled LDS, split epilogue ----------------
// A[M x K] @ Wt^T + bias. Column gc: m=gc>>dshift, off=gc&(D-1);
//   m=0 (Q) -> QS[row][off]; m=1 (K) -> KV[row][off];
//   m=2 (V) -> KV[row][D+off]; m=3 (S) -> QS[row][D+off]. Row stride 2D.
// K must be a multiple of 64.
__global__ __launch_bounds__(256)
void gemm_mfma_kernel(const __half* __restrict__ A, int lda,
                      const __half* __restrict__ Wt,
                      const float* __restrict__ bias,
                      __half* __restrict__ QS, __half* __restrict__ KV,
                      int dshift, int K) {
  __shared__ __align__(16) __half As[2][128 * 32];
  __shared__ __align__(16) __half Bs[2][128 * 32];
  int tid = threadIdx.x;
  int wave = tid >> 6, lane = tid & 63;
  int wr = wave >> 1, wc = wave & 1;
  int m0 = blockIdx.x * 128;
  int n0 = blockIdx.y * 128;
  int lr = lane >> 2;                          // row within 16-row chunk
  int lkw = (((lane & 3) ^ (lr & 3)) << 3);    // swizzled k offset (halves)
  int quad = lane >> 4, rr = lane & 15;
  int sw = (rr & 3) << 3;                      // read-side swizzle (halves)

  f32x4 acc[4][4] = {};

  for (int kt = 0; kt < K; kt += 64) {
#pragma unroll
    for (int h = 0; h < 2; ++h) {
#pragma unroll
      for (int p = 0; p < 2; ++p) {
        int chunk = p * 64 + wave * 16;  // wave-uniform
        const __half* ga = A + (size_t)(m0 + chunk + lr) * lda + kt + h * 32 + lkw;
        load_lds16(ga, &As[h][chunk * 32]);
        const __half* gb = Wt + (size_t)(n0 + chunk + lr) * K + kt + h * 32 + lkw;
        load_lds16(gb, &Bs[h][chunk * 32]);
      }
    }
    __syncthreads();
#pragma unroll
    for (int h = 0; h < 2; ++h) {
      f16x8 a[4], b[4];
#pragma unroll
      for (int i = 0; i < 4; ++i)
        a[i] = *(const f16x8*)&As[h][(wr * 64 + i * 16 + rr) * 32 + ((quad << 3) ^ sw)];
#pragma unroll
      for (int j = 0; j < 4; ++j)
        b[j] = *(const f16x8*)&Bs[h][(wc * 64 + j * 16 + rr) * 32 + ((quad << 3) ^ sw)];
#pragma unroll
      for (int i = 0; i < 4; ++i)
#pragma unroll
        for (int j = 0; j < 4; ++j)
          acc[i][j] = __builtin_amdgcn_mfma_f32_16x16x32_f16(a[i], b[j], acc[i][j], 0, 0, 0);
    }
    __syncthreads();
  }

  // C/D layout: col = lane&15, row = (lane>>4)*4 + reg
  int col = lane & 15, rb = (lane >> 4) * 4;
  int D = 1 << dshift;
  int rstride = D << 1;
#pragma unroll
  for (int j = 0; j < 4; ++j) {
    int gc = n0 + wc * 64 + j * 16 + col;
    float bj = bias[gc];
    int mseg = gc >> dshift;
    int off = gc & (D - 1);
    bool toKV = (mseg == 1) || (mseg == 2);
    __half* base = toKV ? (KV + off + (mseg == 2 ? D : 0))
                        : (QS + off + (mseg == 3 ? D : 0));
#pragma unroll
    for (int i = 0; i < 4; ++i) {
#pragma unroll
      for (int r = 0; r < 4; ++r) {
        int gr = m0 + wr * 64 + i * 16 + rb + r;
        base[(size_t)gr * rstride] = __float2half(acc[i][j][r] + bj);
      }
    }
  }
}

// ---------------- attention H=8 C=64: one WAVE per node, 2-pair pipeline ----------------
// QS rows [Q(512)|S(512)], KV rows [K(512)|V(512)], stride 1024.
__global__ __launch_bounds__(256)
void attn_h8_kernel(const __half* __restrict__ QS, const __half* __restrict__ KV,
                    const int* __restrict__ rowptr, const int* __restrict__ col,
                    __half* __restrict__ Hout, int N) {
  int n = blockIdx.x * 4 + (threadIdx.x >> 6);
  if (n >= N) return;
  int lane = threadIdx.x & 63;
  size_t rbase = (size_t)n * 1024 + lane * 8;

  f16x8 qv = __builtin_nontemporal_load((const f16x8*)(QS + rbase));
  float qf[8];
#pragma unroll
  for (int j = 0; j < 8; ++j) qf[j] = (float)qv[j];

  int e0 = rowptr[n], e1 = rowptr[n + 1];
  float m = -INFINITY, l = 0.f;
  float o[8] = {};

  f16x8 ka = {}, va = {}, kb = {}, vb = {};
  int i = e0;
  if (i < e1) {
    const __half* p = KV + (size_t)col[i] * 1024 + lane * 8;
    ka = *(const f16x8*)p; va = *(const f16x8*)(p + 512);
  }
  if (i + 1 < e1) {
    const __half* p = KV + (size_t)col[i + 1] * 1024 + lane * 8;
    kb = *(const f16x8*)p; vb = *(const f16x8*)(p + 512);
  }

  while (i < e1) {
    int rem = e1 - i;
    f16x8 kc = {}, vc = {}, kd = {}, vd = {};
    if (rem > 2) {
      const __half* p = KV + (size_t)col[i + 2] * 1024 + lane * 8;
      kc = *(const f16x8*)p; vc = *(const f16x8*)(p + 512);
    }
    if (rem > 3) {
      const __half* p = KV + (size_t)col[i + 3] * 1024 + lane * 8;
      kd = *(const f16x8*)p; vd = *(const f16x8*)(p + 512);
    }
    float pa = 0.f, pb = 0.f;
#pragma unroll
    for (int j = 0; j < 8; ++j) { pa += (float)ka[j] * qf[j]; pb += (float)kb[j] * qf[j]; }
    pa += __shfl_xor(pa, 1, 64); pb += __shfl_xor(pb, 1, 64);
    pa += __shfl_xor(pa, 2, 64); pb += __shfl_xor(pb, 2, 64);
    pa += __shfl_xor(pa, 4, 64); pb += __shfl_xor(pb, 4, 64);
    float a0 = pa * 0.125f;
    if (rem > 1) {
      float a1 = pb * 0.125f;
      float mn = fmaxf(m, fmaxf(a0, a1));
      float sc = __expf(m - mn);
      float ea = __expf(a0 - mn), eb = __expf(a1 - mn);
      l = l * sc + ea + eb;
#pragma unroll
      for (int c = 0; c < 8; ++c)
        o[c] = o[c] * sc + ea * (float)va[c] + eb * (float)vb[c];
      m = mn;
    } else {
      float mn = fmaxf(m, a0);
      float sc = __expf(m - mn);
      float ea = __expf(a0 - mn);
      l = l * sc + ea;
#pragma unroll
      for (int c = 0; c < 8; ++c) o[c] = o[c] * sc + ea * (float)va[c];
      m = mn;
    }
    ka = kc; va = vc; kb = kd; vb = vd;
    i += 2;
  }

  float inv = 1.f / (l + 1e-16f);
  f16x8 sv = __builtin_nontemporal_load((const f16x8*)(QS + rbase + 512));
  f16x8 hv;
#pragma unroll
  for (int c = 0; c < 8; ++c) {
    float r = o[c] * inv + (float)sv[c];
    hv[c] = (_Float16)fmaxf(r, 0.f);
  }
  __builtin_nontemporal_store(hv, (f16x8*)(Hout + (size_t)n * 512 + lane * 8));
}

// ---------------- attention H=1 C=64: 8-lane group per node, pipelined ----------------
// QS rows [Q(64)|S(64)], KV rows [K(64)|V(64)], stride 128. fp32 out.
__global__ __launch_bounds__(256)
void attn_h1_kernel(const __half* __restrict__ QS, const __half* __restrict__ KV,
                    const int* __restrict__ rowptr, const int* __restrict__ col,
                    float* __restrict__ out, int N) {
  int n = (blockIdx.x * 256 + threadIdx.x) >> 3;
  if (n >= N) return;
  int gl = threadIdx.x & 7;
  size_t rbase = (size_t)n * 128 + gl * 8;

  f16x8 qv = __builtin_nontemporal_load((const f16x8*)(QS + rbase));
  float qf[8];
#pragma unroll
  for (int j = 0; j < 8; ++j) qf[j] = (float)qv[j];

  int e0 = rowptr[n], e1 = rowptr[n + 1];
  float m = -INFINITY, l = 0.f;
  float o[8] = {};

  f16x8 ka = {}, va = {}, kb = {}, vb = {};
  int i = e0;
  if (i < e1) {
    const __half* p = KV + (size_t)col[i] * 128 + gl * 8;
    ka = *(const f16x8*)p; va = *(const f16x8*)(p + 64);
  }
  if (i + 1 < e1) {
    const __half* p = KV + (size_t)col[i + 1] * 128 + gl * 8;
    kb = *(const f16x8*)p; vb = *(const f16x8*)(p + 64);
  }

  while (i < e1) {
    int rem = e1 - i;
    f16x8 kc = {}, vc = {}, kd = {}, vd = {};
    if (rem > 2) {
      const __half* p = KV + (size_t)col[i + 2] * 128 + gl * 8;
      kc = *(const f16x8*)p; vc = *(const f16x8*)(p + 64);
    }
    if (rem > 3) {
      const __half* p = KV + (size_t)col[i + 3] * 128 + gl * 8;
      kd = *(const f16x8*)p; vd = *(const f16x8*)(p + 64);
    }
    float pa = 0.f, pb = 0.f;
#pragma unroll
    for (int j = 0; j < 8; ++j) { pa += (float)ka[j] * qf[j]; pb += (float)kb[j] * qf[j]; }
    pa += __shfl_xor(pa, 1, 64); pb += __shfl_xor(pb, 1, 64);
    pa += __shfl_xor(pa, 2, 64); pb += __shfl_xor(pb, 2, 64);
    pa += __shfl_xor(pa, 4, 64); pb += __shfl_xor(pb, 4, 64);
    float a0 = pa * 0.125f;
    if (rem > 1) {
      float a1 = pb * 0.125f;
      float mn = fmaxf(m, fmaxf(a0, a1));
      float sc = __expf(m - mn);
      float ea = __expf(a0 - mn), eb = __expf(a1 - mn);
      l = l * sc + ea + eb;
#pragma unroll
      for (int c = 0; c < 8; ++c)
        o[c] = o[c] * sc + ea * (float)va[c] + eb * (float)vb[c];
      m = mn;
    } else {
      float mn = fmaxf(m, a0);
      float sc = __expf(m - mn);
      float ea = __expf(a0 - mn);
      l = l * sc + ea;
#pragma unroll
      for (int c = 0; c < 8; ++c) o[c] = o[c] * sc + ea * (float)va[c];
      m = mn;
    }
    ka = kc; va = vc; kb = kd; vb = vd;
    i += 2;
  }

  float inv = 1.f / (l + 1e-16f);
  f16x8 sv = __builtin_nontemporal_load((const f16x8*)(QS + rbase + 64));
  f32x4 r0, r1;
#pragma unroll
  for (int c = 0; c < 4; ++c) r0[c] = o[c] * inv + (float)sv[c];
#pragma unroll
  for (int c = 0; c < 4; ++c) r1[c] = o[c + 4] * inv + (float)sv[c + 4];
  float* op = out + (size_t)n * 64 + gl * 8;
  *(f32x4*)op = r0;
  *(f32x4*)(op + 4) = r1;
}

extern "C" void kernel_launch(void* const* d_in, const int* in_sizes, int n_in,
                              void* d_out, int out_size, void* d_ws, size_t ws_size,
                              hipStream_t stream) {
  const float* x = (const float*)d_in[0];
  const int* ei = (const int*)d_in[1];
  const int N = in_sizes[0] / 128;
  const int E = in_sizes[1] / 2;
  const int Npad = ((N + 127) / 128) * 128;
  const int* srcp = ei;
  const int* dstp = ei + E;

  const float* Wq0 = (const float*)d_in[2];  const float* bq0 = (const float*)d_in[3];
  const float* Wk0 = (const float*)d_in[4];  const float* bk0 = (const float*)d_in[5];
  const float* Wv0 = (const float*)d_in[6];  const float* bv0 = (const float*)d_in[7];
  const float* Ws0 = (const float*)d_in[8];  const float* bs0 = (const float*)d_in[9];
  const float* Wq1 = (const float*)d_in[10]; const float* bq1 = (const float*)d_in[11];
  const float* Wk1 = (const float*)d_in[12]; const float* bk1 = (const float*)d_in[13];
  const float* Wv1 = (const float*)d_in[14]; const float* bv1 = (const float*)d_in[15];
  const float* Ws1 = (const float*)d_in[16]; const float* bs1 = (const float*)d_in[17];
  const float* Wq2 = (const float*)d_in[18]; const float* bq2 = (const float*)d_in[19];
  const float* Wk2 = (const float*)d_in[20]; const float* bk2 = (const float*)d_in[21];
  const float* Wv2 = (const float*)d_in[22]; const float* bv2 = (const float*)d_in[23];
  const float* Ws2 = (const float*)d_in[24]; const float* bs2 = (const float*)d_in[25];

  // ---- workspace layout (~251 MiB) ----
  char* p = (char*)d_ws;
  __half* QS = (__half*)p;               p += (size_t)Npad * 1024 * 2;  // 102.5 MB
  __half* KV = (__half*)p;               p += (size_t)Npad * 1024 * 2;  // 102.5 MB
  __half* H  = (__half*)p;               p += (size_t)Npad * 512 * 2;   // 51.25 MB
  __half* X16 = H;  // aliases H; dead before H is first written
  __half* Wt = (__half*)p;               p += (size_t)1441792 * 2;      // 2.88 MB
  float* bias_arena = (float*)p;         p += 4352 * 4;
  int* deg    = (int*)p;                 p += (size_t)N * 4;
  int* rowptr = (int*)p;                 p += (size_t)(N + 1) * 4;
  int* cursor = (int*)p;                 p += (size_t)(N + 1) * 4;
  int* colv   = (int*)p;                 p += (size_t)E * 4;
  size_t need = p - (char*)d_ws;
  if (ws_size < need) {
    fprintf(stderr, "kernel_launch: ws_size=%zu < need=%zu — aborting cleanly\n",
            ws_size, need);
    return;
  }

  // ---- prep: all weights/biases in 2 launches ----
  transpose_all_kernel<<<dim3(16, 16, 12), 256, 0, stream>>>(
      Wq0, Wk0, Wv0, Ws0, Wq1, Wk1, Wv1, Ws1, Wq2, Wk2, Wv2, Ws2, Wt);
  bias_all_kernel<<<12, 256, 0, stream>>>(
      bq0, bk0, bv0, bs0, bq1, bk1, bv1, bs1, bq2, bk2, bv2, bs2, bias_arena);
  convert_x_kernel<<<(Npad * 128 / 8 + 255) / 256, 256, 0, stream>>>(x, X16, N, Npad);
  zero_pad_kernel<<<((Npad - N) * 512 + 255) / 256, 256, 0, stream>>>(
      H, N * 512, (Npad - N) * 512);

  // ---- CSR build ----
  zero_int_kernel<<<(N + 255) / 256, 256, 0, stream>>>(deg, N);
  degree_kernel<<<(E + 255) / 256, 256, 0, stream>>>(dstp, deg, E);
  exscan_kernel<<<1, 1024, 0, stream>>>(deg, rowptr, cursor, N);
  scatter_kernel<<<(E + 255) / 256, 256, 0, stream>>>(srcp, dstp, cursor, colv, E);

  const int mtiles = Npad / 128;
  __half* Wt0 = Wt;
  __half* Wt1 = Wt + 262144;
  __half* Wt2 = Wt + 1310720;

  // ---- layer 0: K=128, D=512 ----
  gemm_mfma_kernel<<<dim3(mtiles, 2048 / 128), 256, 0, stream>>>(
      X16, 128, Wt0, bias_arena, QS, KV, 9, 128);
  attn_h8_kernel<<<(N + 3) / 4, 256, 0, stream>>>(QS, KV, rowptr, colv, H, N);

  // ---- layer 1: K=512, D=512 ----
  gemm_mfma_kernel<<<dim3(mtiles, 2048 / 128), 256, 0, stream>>>(
      H, 512, Wt1, bias_arena + 2048, QS, KV, 9, 512);
  attn_h8_kernel<<<(N + 3) / 4, 256, 0, stream>>>(QS, KV, rowptr, colv, H, N);

  // ---- layer 2: K=512, D=64 ----
  gemm_mfma_kernel<<<dim3(mtiles, 256 / 128), 256, 0, stream>>>(
      H, 512, Wt2, bias_arena + 4096, QS, KV, 6, 512);
  attn_h1_kernel<<<(N + 31) / 32, 256, 0, stream>>>(QS, KV, rowptr, colv,
                                                    (float*)d_out, N);
}

// Round 9
// 1072.757 us; speedup vs baseline: 1.0875x; 1.0396x over previous
//
#include <hip/hip_runtime.h>
#include <hip/hip_fp16.h>
#include <math.h>
#include <stdio.h>

// N=50000, E=800000, IN=128, C=64, H=8, H*C=512
// Round 9: (a) full GEMM LDS XOR swizzle quad^(row&3)^((row>>2)&3) — kills the
// residual 4-way read conflict (rows +-4 aliased); (b) gemm grid swapped so
// n-tiles are fast-varying (A-tile L2 reuse across XCDs); (c) launch diet.
// Attention kernels unchanged (pinned at ~240us / 822MB across 3 variants).

using f16x8 = __attribute__((ext_vector_type(8))) _Float16;
using f32x4 = __attribute__((ext_vector_type(4))) float;

__device__ __forceinline__ void load_lds16(const void* g, void* l) {
  __builtin_amdgcn_global_load_lds((const __attribute__((address_space(1))) void*)g,
                                   (__attribute__((address_space(3))) void*)l,
                                   16, 0, 0);
}

// ---------------- CSR build ----------------
__global__ void degree_kernel(const int* __restrict__ dst, int* __restrict__ deg, int E) {
  int e = blockIdx.x * blockDim.x + threadIdx.x;
  if (e < E) atomicAdd(&deg[dst[e]], 1);
}

__global__ __launch_bounds__(1024)
void exscan_kernel(const int* __restrict__ deg, int* __restrict__ rowptr,
                   int* __restrict__ cursor, int n) {
  __shared__ int tmp[1024];
  int tid = threadIdx.x;
  int chunk = (n + 1023) / 1024;
  int lo = tid * chunk;
  int hi = min(n, lo + chunk);
  int s = 0;
  for (int i = lo; i < hi; ++i) s += deg[i];
  int mysum = s;
  tmp[tid] = s;
  __syncthreads();
  for (int off = 1; off < 1024; off <<= 1) {
    int v = (tid >= off) ? tmp[tid - off] : 0;
    __syncthreads();
    tmp[tid] += v;
    __syncthreads();
  }
  int run = tmp[tid] - mysum;
  if (tid == 0) { rowptr[0] = 0; cursor[0] = 0; }
  for (int i = lo; i < hi; ++i) {
    run += deg[i];
    rowptr[i + 1] = run;
    cursor[i + 1] = run;
  }
}

__global__ void scatter_kernel(const int* __restrict__ src, const int* __restrict__ dst,
                               int* __restrict__ cursor, int* __restrict__ col, int E) {
  int e = blockIdx.x * blockDim.x + threadIdx.x;
  if (e < E) {
    int pos = atomicAdd(&cursor[dst[e]], 1);
    col[pos] = src[e];
  }
}

// ---------------- prep kernels ----------------
// job 1: x fp32 -> X16 fp16 (pad rows zeroed); job 2: zero H pad rows.
// X16 aliases head of H; regions are disjoint.
__global__ void prep_x_kernel(const float* __restrict__ x, __half* __restrict__ X16,
                              __half* __restrict__ H, int N, int Npad) {
  int t = blockIdx.x * 256 + threadIdx.x;
  int nx = Npad * 128 / 8;
  int nz = (Npad - N) * 512 / 8;
  if (t < nx) {
    int i = t * 8;
    int row = i >> 7;
    f16x8 hv;
    if (row < N) {
      const float* xp = x + i;
#pragma unroll
      for (int j = 0; j < 8; ++j) hv[j] = (_Float16)xp[j];
    } else {
#pragma unroll
      for (int j = 0; j < 8; ++j) hv[j] = (_Float16)0.f;
    }
    *(f16x8*)(X16 + i) = hv;
  } else if (t < nx + nz) {
    int i = (t - nx) * 8;
    f16x8 z = {};
    *(f16x8*)(H + (size_t)N * 512 + i) = z;
  }
}

// ALL 12 weight transposes in one launch. z = layer*4 + m.
__global__ __launch_bounds__(256)
void transpose_all_kernel(
    const float* __restrict__ Wq0, const float* __restrict__ Wk0,
    const float* __restrict__ Wv0, const float* __restrict__ Ws0,
    const float* __restrict__ Wq1, const float* __restrict__ Wk1,
    const float* __restrict__ Wv1, const float* __restrict__ Ws1,
    const float* __restrict__ Wq2, const float* __restrict__ Wk2,
    const float* __restrict__ Wv2, const float* __restrict__ Ws2,
    __half* __restrict__ Wt) {
  int z = blockIdx.z;
  int layer = z >> 2, m = z & 3;
  int K = (layer == 0) ? 128 : 512;
  int D = (layer == 2) ? 64 : 512;
  int c0 = blockIdx.x * 32, k0 = blockIdx.y * 32;
  if (c0 >= D || k0 >= K) return;
  const float* W;
  switch (z) {
    case 0: W = Wq0; break; case 1: W = Wk0; break;
    case 2: W = Wv0; break; case 3: W = Ws0; break;
    case 4: W = Wq1; break; case 5: W = Wk1; break;
    case 6: W = Wv1; break; case 7: W = Ws1; break;
    case 8: W = Wq2; break; case 9: W = Wk2; break;
    case 10: W = Wv2; break; default: W = Ws2; break;
  }
  __half* dstBase = Wt + ((layer == 0) ? 0 : (layer == 1) ? 262144 : 1310720);
  __shared__ float t[32][33];
  int tx = threadIdx.x & 31, ty = threadIdx.x >> 5;  // (32,8)
#pragma unroll
  for (int r = 0; r < 4; ++r)
    t[ty + 8 * r][tx] = W[(size_t)(k0 + ty + 8 * r) * D + c0 + tx];
  __syncthreads();
#pragma unroll
  for (int r = 0; r < 4; ++r)
    dstBase[(size_t)(m * D + c0 + ty + 8 * r) * K + k0 + tx] =
        __float2half(t[tx][ty + 8 * r]);
}

__global__ void bias_all_kernel(
    const float* __restrict__ b0, const float* __restrict__ b1,
    const float* __restrict__ b2, const float* __restrict__ b3,
    const float* __restrict__ b4, const float* __restrict__ b5,
    const float* __restrict__ b6, const float* __restrict__ b7,
    const float* __restrict__ b8, const float* __restrict__ b9,
    const float* __restrict__ b10, const float* __restrict__ b11,
    float* __restrict__ bias_arena) {
  int z = blockIdx.x;
  int layer = z >> 2, m = z & 3;
  int D = (layer == 2) ? 64 : 512;
  const float* b;
  switch (z) {
    case 0: b = b0; break; case 1: b = b1; break;
    case 2: b = b2; break; case 3: b = b3; break;
    case 4: b = b4; break; case 5: b = b5; break;
    case 6: b = b6; break; case 7: b = b7; break;
    case 8: b = b8; break; case 9: b = b9; break;
    case 10: b = b10; break; default: b = b11; break;
  }
  float* dst = bias_arena + ((layer == 0) ? 0 : (layer == 1) ? 2048 : 4096) + m * D;
  for (int c = threadIdx.x; c < D; c += 256) dst[c] = b[c];
}

// ---------------- MFMA GEMM, BK=64, full-XOR LDS swizzle, split epilogue ----------------
// grid = (ntiles, mtiles): n fast-varying so blocks sharing an A-tile are
// dispatched consecutively (A L2 reuse). K multiple of 64.
// Swizzle: LDS quad slot q' = q ^ (row&3) ^ ((row>>2)&3) — 2-way max (free).
__global__ __launch_bounds__(256, 4)
void gemm_mfma_kernel(const __half* __restrict__ A, int lda,
                      const __half* __restrict__ Wt,
                      const float* __restrict__ bias,
                      __half* __restrict__ QS, __half* __restrict__ KV,
                      int dshift, int K) {
  __shared__ __align__(16) __half As[2][128 * 32];
  __shared__ __align__(16) __half Bs[2][128 * 32];
  int tid = threadIdx.x;
  int wave = tid >> 6, lane = tid & 63;
  int wr = wave >> 1, wc = wave & 1;
  int n0 = blockIdx.x * 128;
  int m0 = blockIdx.y * 128;
  int lr = lane >> 2;  // row within 16-row staging chunk
  int lkw = (((lane & 3) ^ (lr & 3) ^ ((lr >> 2) & 3)) << 3);  // swizzled k off
  int quad = lane >> 4, rr = lane & 15;
  int sw = (((rr & 3) ^ ((rr >> 2) & 3)) << 3);                // read-side

  f32x4 acc[4][4] = {};

  for (int kt = 0; kt < K; kt += 64) {
#pragma unroll
    for (int h = 0; h < 2; ++h) {
#pragma unroll
      for (int p = 0; p < 2; ++p) {
        int chunk = p * 64 + wave * 16;  // wave-uniform
        const __half* ga = A + (size_t)(m0 + chunk + lr) * lda + kt + h * 32 + lkw;
        load_lds16(ga, &As[h][chunk * 32]);
        const __half* gb = Wt + (size_t)(n0 + chunk + lr) * K + kt + h * 32 + lkw;
        load_lds16(gb, &Bs[h][chunk * 32]);
      }
    }
    __syncthreads();
#pragma unroll
    for (int h = 0; h < 2; ++h) {
      f16x8 a[4], b[4];
#pragma unroll
      for (int i = 0; i < 4; ++i)
        a[i] = *(const f16x8*)&As[h][(wr * 64 + i * 16 + rr) * 32 + ((quad << 3) ^ sw)];
#pragma unroll
      for (int j = 0; j < 4; ++j)
        b[j] = *(const f16x8*)&Bs[h][(wc * 64 + j * 16 + rr) * 32 + ((quad << 3) ^ sw)];
#pragma unroll
      for (int i = 0; i < 4; ++i)
#pragma unroll
        for (int j = 0; j < 4; ++j)
          acc[i][j] = __builtin_amdgcn_mfma_f32_16x16x32_f16(a[i], b[j], acc[i][j], 0, 0, 0);
    }
    __syncthreads();
  }

  // C/D layout: col = lane&15, row = (lane>>4)*4 + reg
  int col = lane & 15, rb = (lane >> 4) * 4;
  int D = 1 << dshift;
  int rstride = D << 1;
#pragma unroll
  for (int j = 0; j < 4; ++j) {
    int gc = n0 + wc * 64 + j * 16 + col;
    float bj = bias[gc];
    int mseg = gc >> dshift;
    int off = gc & (D - 1);
    bool toKV = (mseg == 1) || (mseg == 2);
    __half* base = toKV ? (KV + off + (mseg == 2 ? D : 0))
                        : (QS + off + (mseg == 3 ? D : 0));
#pragma unroll
    for (int i = 0; i < 4; ++i) {
#pragma unroll
      for (int r = 0; r < 4; ++r) {
        int gr = m0 + wr * 64 + i * 16 + rb + r;
        base[(size_t)gr * rstride] = __float2half(acc[i][j][r] + bj);
      }
    }
  }
}

// ---------------- attention H=8 C=64: one WAVE per node, 2-pair pipeline ----------------
__global__ __launch_bounds__(256)
void attn_h8_kernel(const __half* __restrict__ QS, const __half* __restrict__ KV,
                    const int* __restrict__ rowptr, const int* __restrict__ col,
                    __half* __restrict__ Hout, int N) {
  int n = blockIdx.x * 4 + (threadIdx.x >> 6);
  if (n >= N) return;
  int lane = threadIdx.x & 63;
  size_t rbase = (size_t)n * 1024 + lane * 8;

  f16x8 qv = __builtin_nontemporal_load((const f16x8*)(QS + rbase));
  float qf[8];
#pragma unroll
  for (int j = 0; j < 8; ++j) qf[j] = (float)qv[j];

  int e0 = rowptr[n], e1 = rowptr[n + 1];
  float m = -INFINITY, l = 0.f;
  float o[8] = {};

  f16x8 ka = {}, va = {}, kb = {}, vb = {};
  int i = e0;
  if (i < e1) {
    const __half* p = KV + (size_t)col[i] * 1024 + lane * 8;
    ka = *(const f16x8*)p; va = *(const f16x8*)(p + 512);
  }
  if (i + 1 < e1) {
    const __half* p = KV + (size_t)col[i + 1] * 1024 + lane * 8;
    kb = *(const f16x8*)p; vb = *(const f16x8*)(p + 512);
  }

  while (i < e1) {
    int rem = e1 - i;
    f16x8 kc = {}, vc = {}, kd = {}, vd = {};
    if (rem > 2) {
      const __half* p = KV + (size_t)col[i + 2] * 1024 + lane * 8;
      kc = *(const f16x8*)p; vc = *(const f16x8*)(p + 512);
    }
    if (rem > 3) {
      const __half* p = KV + (size_t)col[i + 3] * 1024 + lane * 8;
      kd = *(const f16x8*)p; vd = *(const f16x8*)(p + 512);
    }
    float pa = 0.f, pb = 0.f;
#pragma unroll
    for (int j = 0; j < 8; ++j) { pa += (float)ka[j] * qf[j]; pb += (float)kb[j] * qf[j]; }
    pa += __shfl_xor(pa, 1, 64); pb += __shfl_xor(pb, 1, 64);
    pa += __shfl_xor(pa, 2, 64); pb += __shfl_xor(pb, 2, 64);
    pa += __shfl_xor(pa, 4, 64); pb += __shfl_xor(pb, 4, 64);
    float a0 = pa * 0.125f;
    if (rem > 1) {
      float a1 = pb * 0.125f;
      float mn = fmaxf(m, fmaxf(a0, a1));
      float sc = __expf(m - mn);
      float ea = __expf(a0 - mn), eb = __expf(a1 - mn);
      l = l * sc + ea + eb;
#pragma unroll
      for (int c = 0; c < 8; ++c)
        o[c] = o[c] * sc + ea * (float)va[c] + eb * (float)vb[c];
      m = mn;
    } else {
      float mn = fmaxf(m, a0);
      float sc = __expf(m - mn);
      float ea = __expf(a0 - mn);
      l = l * sc + ea;
#pragma unroll
      for (int c = 0; c < 8; ++c) o[c] = o[c] * sc + ea * (float)va[c];
      m = mn;
    }
    ka = kc; va = vc; kb = kd; vb = vd;
    i += 2;
  }

  float inv = 1.f / (l + 1e-16f);
  f16x8 sv = __builtin_nontemporal_load((const f16x8*)(QS + rbase + 512));
  f16x8 hv;
#pragma unroll
  for (int c = 0; c < 8; ++c) {
    float r = o[c] * inv + (float)sv[c];
    hv[c] = (_Float16)fmaxf(r, 0.f);
  }
  __builtin_nontemporal_store(hv, (f16x8*)(Hout + (size_t)n * 512 + lane * 8));
}

// ---------------- attention H=1 C=64: 8-lane group per node, pipelined ----------------
__global__ __launch_bounds__(256)
void attn_h1_kernel(const __half* __restrict__ QS, const __half* __restrict__ KV,
                    const int* __restrict__ rowptr, const int* __restrict__ col,
                    float* __restrict__ out, int N) {
  int n = (blockIdx.x * 256 + threadIdx.x) >> 3;
  if (n >= N) return;
  int gl = threadIdx.x & 7;
  size_t rbase = (size_t)n * 128 + gl * 8;

  f16x8 qv = __builtin_nontemporal_load((const f16x8*)(QS + rbase));
  float qf[8];
#pragma unroll
  for (int j = 0; j < 8; ++j) qf[j] = (float)qv[j];

  int e0 = rowptr[n], e1 = rowptr[n + 1];
  float m = -INFINITY, l = 0.f;
  float o[8] = {};

  f16x8 ka = {}, va = {}, kb = {}, vb = {};
  int i = e0;
  if (i < e1) {
    const __half* p = KV + (size_t)col[i] * 128 + gl * 8;
    ka = *(const f16x8*)p; va = *(const f16x8*)(p + 64);
  }
  if (i + 1 < e1) {
    const __half* p = KV + (size_t)col[i + 1] * 128 + gl * 8;
    kb = *(const f16x8*)p; vb = *(const f16x8*)(p + 64);
  }

  while (i < e1) {
    int rem = e1 - i;
    f16x8 kc = {}, vc = {}, kd = {}, vd = {};
    if (rem > 2) {
      const __half* p = KV + (size_t)col[i + 2] * 128 + gl * 8;
      kc = *(const f16x8*)p; vc = *(const f16x8*)(p + 64);
    }
    if (rem > 3) {
      const __half* p = KV + (size_t)col[i + 3] * 128 + gl * 8;
      kd = *(const f16x8*)p; vd = *(const f16x8*)(p + 64);
    }
    float pa = 0.f, pb = 0.f;
#pragma unroll
    for (int j = 0; j < 8; ++j) { pa += (float)ka[j] * qf[j]; pb += (float)kb[j] * qf[j]; }
    pa += __shfl_xor(pa, 1, 64); pb += __shfl_xor(pb, 1, 64);
    pa += __shfl_xor(pa, 2, 64); pb += __shfl_xor(pb, 2, 64);
    pa += __shfl_xor(pa, 4, 64); pb += __shfl_xor(pb, 4, 64);
    float a0 = pa * 0.125f;
    if (rem > 1) {
      float a1 = pb * 0.125f;
      float mn = fmaxf(m, fmaxf(a0, a1));
      float sc = __expf(m - mn);
      float ea = __expf(a0 - mn), eb = __expf(a1 - mn);
      l = l * sc + ea + eb;
#pragma unroll
      for (int c = 0; c < 8; ++c)
        o[c] = o[c] * sc + ea * (float)va[c] + eb * (float)vb[c];
      m = mn;
    } else {
      float mn = fmaxf(m, a0);
      float sc = __expf(m - mn);
      float ea = __expf(a0 - mn);
      l = l * sc + ea;
#pragma unroll
      for (int c = 0; c < 8; ++c) o[c] = o[c] * sc + ea * (float)va[c];
      m = mn;
    }
    ka = kc; va = vc; kb = kd; vb = vd;
    i += 2;
  }

  float inv = 1.f / (l + 1e-16f);
  f16x8 sv = __builtin_nontemporal_load((const f16x8*)(QS + rbase + 64));
  f32x4 r0, r1;
#pragma unroll
  for (int c = 0; c < 4; ++c) r0[c] = o[c] * inv + (float)sv[c];
#pragma unroll
  for (int c = 0; c < 4; ++c) r1[c] = o[c + 4] * inv + (float)sv[c + 4];
  float* op = out + (size_t)n * 64 + gl * 8;
  *(f32x4*)op = r0;
  *(f32x4*)(op + 4) = r1;
}

extern "C" void kernel_launch(void* const* d_in, const int* in_sizes, int n_in,
                              void* d_out, int out_size, void* d_ws, size_t ws_size,
                              hipStream_t stream) {
  const float* x = (const float*)d_in[0];
  const int* ei = (const int*)d_in[1];
  const int N = in_sizes[0] / 128;
  const int E = in_sizes[1] / 2;
  const int Npad = ((N + 127) / 128) * 128;
  const int* srcp = ei;
  const int* dstp = ei + E;

  const float* Wq0 = (const float*)d_in[2];  const float* bq0 = (const float*)d_in[3];
  const float* Wk0 = (const float*)d_in[4];  const float* bk0 = (const float*)d_in[5];
  const float* Wv0 = (const float*)d_in[6];  const float* bv0 = (const float*)d_in[7];
  const float* Ws0 = (const float*)d_in[8];  const float* bs0 = (const float*)d_in[9];
  const float* Wq1 = (const float*)d_in[10]; const float* bq1 = (const float*)d_in[11];
  const float* Wk1 = (const float*)d_in[12]; const float* bk1 = (const float*)d_in[13];
  const float* Wv1 = (const float*)d_in[14]; const float* bv1 = (const float*)d_in[15];
  const float* Ws1 = (const float*)d_in[16]; const float* bs1 = (const float*)d_in[17];
  const float* Wq2 = (const float*)d_in[18]; const float* bq2 = (const float*)d_in[19];
  const float* Wk2 = (const float*)d_in[20]; const float* bk2 = (const float*)d_in[21];
  const float* Wv2 = (const float*)d_in[22]; const float* bv2 = (const float*)d_in[23];
  const float* Ws2 = (const float*)d_in[24]; const float* bs2 = (const float*)d_in[25];

  // ---- workspace layout (~259 MB) ----
  char* p = (char*)d_ws;
  __half* QS = (__half*)p;               p += (size_t)Npad * 1024 * 2;  // 102.5 MB
  __half* KV = (__half*)p;               p += (size_t)Npad * 1024 * 2;  // 102.5 MB
  __half* H  = (__half*)p;               p += (size_t)Npad * 512 * 2;   // 51.25 MB
  __half* X16 = H;  // aliases H; dead before H is first written
  __half* Wt = (__half*)p;               p += (size_t)1441792 * 2;      // 2.88 MB
  float* bias_arena = (float*)p;         p += 4352 * 4;
  int* deg    = (int*)p;                 p += (size_t)N * 4;
  int* rowptr = (int*)p;                 p += (size_t)(N + 1) * 4;
  int* cursor = (int*)p;                 p += (size_t)(N + 1) * 4;
  int* colv   = (int*)p;                 p += (size_t)E * 4;
  size_t need = p - (char*)d_ws;
  if (ws_size < need) {
    fprintf(stderr, "kernel_launch: ws_size=%zu < need=%zu — aborting cleanly\n",
            ws_size, need);
    return;
  }

  // ---- prep ----
  transpose_all_kernel<<<dim3(16, 16, 12), 256, 0, stream>>>(
      Wq0, Wk0, Wv0, Ws0, Wq1, Wk1, Wv1, Ws1, Wq2, Wk2, Wv2, Ws2, Wt);
  bias_all_kernel<<<12, 256, 0, stream>>>(
      bq0, bk0, bv0, bs0, bq1, bk1, bv1, bs1, bq2, bk2, bv2, bs2, bias_arena);
  {
    int nwork = Npad * 128 / 8 + (Npad - N) * 512 / 8;
    prep_x_kernel<<<(nwork + 255) / 256, 256, 0, stream>>>(x, X16, H, N, Npad);
  }

  // ---- CSR build ----
  hipMemsetAsync(deg, 0, (size_t)N * 4, stream);
  degree_kernel<<<(E + 255) / 256, 256, 0, stream>>>(dstp, deg, E);
  exscan_kernel<<<1, 1024, 0, stream>>>(deg, rowptr, cursor, N);
  scatter_kernel<<<(E + 255) / 256, 256, 0, stream>>>(srcp, dstp, cursor, colv, E);

  const int mtiles = Npad / 128;
  __half* Wt0 = Wt;
  __half* Wt1 = Wt + 262144;
  __half* Wt2 = Wt + 1310720;

  // ---- layer 0: K=128, D=512 ----
  gemm_mfma_kernel<<<dim3(2048 / 128, mtiles), 256, 0, stream>>>(
      X16, 128, Wt0, bias_arena, QS, KV, 9, 128);
  attn_h8_kernel<<<(N + 3) / 4, 256, 0, stream>>>(QS, KV, rowptr, colv, H, N);

  // ---- layer 1: K=512, D=512 ----
  gemm_mfma_kernel<<<dim3(2048 / 128, mtiles), 256, 0, stream>>>(
      H, 512, Wt1, bias_arena + 2048, QS, KV, 9, 512);
  attn_h8_kernel<<<(N + 3) / 4, 256, 0, stream>>>(QS, KV, rowptr, colv, H, N);

  // ---- layer 2: K=512, D=64 ----
  gemm_mfma_kernel<<<dim3(256 / 128, mtiles), 256, 0, stream>>>(
      H, 512, Wt2, bias_arena + 4096, QS, KV, 6, 512);
  attn_h1_kernel<<<(N + 31) / 32, 256, 0, stream>>>(QS, KV, rowptr, colv,
                                                    (float*)d_out, N);
}

// Round 10
// 1029.946 us; speedup vs baseline: 1.1327x; 1.0416x over previous
//
#include <hip/hip_runtime.h>
#include <hip/hip_fp16.h>
#include <math.h>
#include <stdio.h>

// N=50000, E=800000, IN=128, C=64, H=8, H*C=512
// Round 10: (a) per-layer templated GEMM (distinct names in rocprof),
// (b) layer-0 GEMM stages fp32 x directly (VGPR cvt -> ds_write_b128, same
// swizzled LDS image) — X16/prep_x removed, (c) multi-block exscan,
// (d) merged zero kernel. Attention unchanged (at fabric-path floor).

using f16x8 = __attribute__((ext_vector_type(8))) _Float16;
using f32x4 = __attribute__((ext_vector_type(4))) float;

__device__ __forceinline__ void load_lds16(const void* g, void* l) {
  __builtin_amdgcn_global_load_lds((const __attribute__((address_space(1))) void*)g,
                                   (__attribute__((address_space(3))) void*)l,
                                   16, 0, 0);
}

// ---------------- CSR build ----------------
// zero deg[N] ints + zero H pad rows
__global__ void zero_misc_kernel(int* __restrict__ deg, __half* __restrict__ H,
                                 int N, int Npad) {
  int t = blockIdx.x * 256 + threadIdx.x;
  if (t < N) deg[t] = 0;
  int nz = (Npad - N) * 512 / 8;
  if (t < nz) {
    f16x8 z = {};
    *(f16x8*)(H + (size_t)N * 512 + (size_t)t * 8) = z;
  }
}

__global__ void degree_kernel(const int* __restrict__ dst, int* __restrict__ deg, int E) {
  int e = blockIdx.x * blockDim.x + threadIdx.x;
  if (e < E) atomicAdd(&deg[dst[e]], 1);
}

// multi-block exclusive scan: A) block-local inclusive into rowptr[i+1] + bsum
__global__ __launch_bounds__(256)
void scan_a_kernel(const int* __restrict__ deg, int* __restrict__ rowptr,
                   int* __restrict__ bsum, int n) {
  __shared__ int tmp[256];
  int t = threadIdx.x;
  int i = blockIdx.x * 256 + t;
  int v = (i < n) ? deg[i] : 0;
  tmp[t] = v;
  __syncthreads();
#pragma unroll
  for (int off = 1; off < 256; off <<= 1) {
    int u = (t >= off) ? tmp[t - off] : 0;
    __syncthreads();
    tmp[t] += u;
    __syncthreads();
  }
  if (i < n) rowptr[i + 1] = tmp[t];
  if (t == 255) bsum[blockIdx.x] = tmp[255];
}

// B) single-block exclusive scan of bsum[nb] in place
__global__ __launch_bounds__(256)
void scan_b_kernel(int* __restrict__ bsum, int nb) {
  __shared__ int tmp[256];
  int t = threadIdx.x;
  int v = (t < nb) ? bsum[t] : 0;
  tmp[t] = v;
  __syncthreads();
#pragma unroll
  for (int off = 1; off < 256; off <<= 1) {
    int u = (t >= off) ? tmp[t - off] : 0;
    __syncthreads();
    tmp[t] += u;
    __syncthreads();
  }
  if (t < nb) bsum[t] = tmp[t] - v;  // exclusive
}

// C) add block offsets, fill cursor, rowptr[0]
__global__ __launch_bounds__(256)
void scan_c_kernel(int* __restrict__ rowptr, int* __restrict__ cursor,
                   const int* __restrict__ bsum, int n) {
  int i = blockIdx.x * 256 + threadIdx.x;
  if (i < n) {
    int r = rowptr[i + 1] + bsum[blockIdx.x];
    rowptr[i + 1] = r;
    cursor[i + 1] = r;
  }
  if (i == 0) { rowptr[0] = 0; cursor[0] = 0; }
}

__global__ void scatter_kernel(const int* __restrict__ src, const int* __restrict__ dst,
                               int* __restrict__ cursor, int* __restrict__ col, int E) {
  int e = blockIdx.x * blockDim.x + threadIdx.x;
  if (e < E) {
    int pos = atomicAdd(&cursor[dst[e]], 1);
    col[pos] = src[e];
  }
}

// ---------------- prep: weights/biases ----------------
__global__ __launch_bounds__(256)
void transpose_all_kernel(
    const float* __restrict__ Wq0, const float* __restrict__ Wk0,
    const float* __restrict__ Wv0, const float* __restrict__ Ws0,
    const float* __restrict__ Wq1, const float* __restrict__ Wk1,
    const float* __restrict__ Wv1, const float* __restrict__ Ws1,
    const float* __restrict__ Wq2, const float* __restrict__ Wk2,
    const float* __restrict__ Wv2, const float* __restrict__ Ws2,
    __half* __restrict__ Wt) {
  int z = blockIdx.z;
  int layer = z >> 2, m = z & 3;
  int K = (layer == 0) ? 128 : 512;
  int D = (layer == 2) ? 64 : 512;
  int c0 = blockIdx.x * 32, k0 = blockIdx.y * 32;
  if (c0 >= D || k0 >= K) return;
  const float* W;
  switch (z) {
    case 0: W = Wq0; break; case 1: W = Wk0; break;
    case 2: W = Wv0; break; case 3: W = Ws0; break;
    case 4: W = Wq1; break; case 5: W = Wk1; break;
    case 6: W = Wv1; break; case 7: W = Ws1; break;
    case 8: W = Wq2; break; case 9: W = Wk2; break;
    case 10: W = Wv2; break; default: W = Ws2; break;
  }
  __half* dstBase = Wt + ((layer == 0) ? 0 : (layer == 1) ? 262144 : 1310720);
  __shared__ float t[32][33];
  int tx = threadIdx.x & 31, ty = threadIdx.x >> 5;  // (32,8)
#pragma unroll
  for (int r = 0; r < 4; ++r)
    t[ty + 8 * r][tx] = W[(size_t)(k0 + ty + 8 * r) * D + c0 + tx];
  __syncthreads();
#pragma unroll
  for (int r = 0; r < 4; ++r)
    dstBase[(size_t)(m * D + c0 + ty + 8 * r) * K + k0 + tx] =
        __float2half(t[tx][ty + 8 * r]);
}

__global__ void bias_all_kernel(
    const float* __restrict__ b0, const float* __restrict__ b1,
    const float* __restrict__ b2, const float* __restrict__ b3,
    const float* __restrict__ b4, const float* __restrict__ b5,
    const float* __restrict__ b6, const float* __restrict__ b7,
    const float* __restrict__ b8, const float* __restrict__ b9,
    const float* __restrict__ b10, const float* __restrict__ b11,
    float* __restrict__ bias_arena) {
  int z = blockIdx.x;
  int layer = z >> 2, m = z & 3;
  int D = (layer == 2) ? 64 : 512;
  const float* b;
  switch (z) {
    case 0: b = b0; break; case 1: b = b1; break;
    case 2: b = b2; break; case 3: b = b3; break;
    case 4: b = b4; break; case 5: b = b5; break;
    case 6: b = b6; break; case 7: b = b7; break;
    case 8: b = b8; break; case 9: b = b9; break;
    case 10: b = b10; break; default: b = b11; break;
  }
  float* dst = bias_arena + ((layer == 0) ? 0 : (layer == 1) ? 2048 : 4096) + m * D;
  for (int c = threadIdx.x; c < D; c += 256) dst[c] = b[c];
}

// ---------------- MFMA GEMM, per-layer template ----------------
// LAYER: 0 (A=fp32 x, lda=128, K=128, D=512), 1 (A=H fp16, K=512, D=512),
//        2 (A=H fp16, K=512, D=64).
// grid = (ntiles, mtiles), n fast-varying. Full XOR swizzle (2-way max).
template <int LAYER>
__global__ __launch_bounds__(256, 4)
void gemm_mfma_kernel(const void* __restrict__ Avoid,
                      const __half* __restrict__ Wt,
                      const float* __restrict__ bias,
                      __half* __restrict__ QS, __half* __restrict__ KV,
                      int Nrows) {
  constexpr int K = (LAYER == 0) ? 128 : 512;
  constexpr int dshift = (LAYER == 2) ? 6 : 9;
  constexpr int lda = (LAYER == 0) ? 128 : 512;
  __shared__ __align__(16) __half As[2][128 * 32];
  __shared__ __align__(16) __half Bs[2][128 * 32];
  int tid = threadIdx.x;
  int wave = tid >> 6, lane = tid & 63;
  int wr = wave >> 1, wc = wave & 1;
  int n0 = blockIdx.x * 128;
  int m0 = blockIdx.y * 128;
  int lr = lane >> 2;  // row within 16-row staging chunk
  int lkw = (((lane & 3) ^ (lr & 3) ^ ((lr >> 2) & 3)) << 3);  // swizzled k off
  int quad = lane >> 4, rr = lane & 15;
  int sw = (((rr & 3) ^ ((rr >> 2) & 3)) << 3);                // read-side

  f32x4 acc[4][4] = {};

  for (int kt = 0; kt < K; kt += 64) {
#pragma unroll
    for (int h = 0; h < 2; ++h) {
#pragma unroll
      for (int p = 0; p < 2; ++p) {
        int chunk = p * 64 + wave * 16;  // wave-uniform
        if constexpr (LAYER == 0) {
          // A: fp32 -> fp16 via VGPR (x has only Nrows valid rows)
          int row = m0 + chunk + lr;
          const float* ga = (const float*)Avoid + (size_t)row * lda + kt + h * 32 + lkw;
          f16x8 hv = {};
          if (row < Nrows) {
            float4 f0 = *(const float4*)ga;
            float4 f1 = *(const float4*)(ga + 4);
            hv[0] = (_Float16)f0.x; hv[1] = (_Float16)f0.y;
            hv[2] = (_Float16)f0.z; hv[3] = (_Float16)f0.w;
            hv[4] = (_Float16)f1.x; hv[5] = (_Float16)f1.y;
            hv[6] = (_Float16)f1.z; hv[7] = (_Float16)f1.w;
          }
          *(f16x8*)&As[h][chunk * 32 + lane * 8] = hv;
        } else {
          const __half* ga = (const __half*)Avoid +
                             (size_t)(m0 + chunk + lr) * lda + kt + h * 32 + lkw;
          load_lds16(ga, &As[h][chunk * 32]);
        }
        const __half* gb = Wt + (size_t)(n0 + chunk + lr) * K + kt + h * 32 + lkw;
        load_lds16(gb, &Bs[h][chunk * 32]);
      }
    }
    __syncthreads();
#pragma unroll
    for (int h = 0; h < 2; ++h) {
      f16x8 a[4], b[4];
#pragma unroll
      for (int i = 0; i < 4; ++i)
        a[i] = *(const f16x8*)&As[h][(wr * 64 + i * 16 + rr) * 32 + ((quad << 3) ^ sw)];
#pragma unroll
      for (int j = 0; j < 4; ++j)
        b[j] = *(const f16x8*)&Bs[h][(wc * 64 + j * 16 + rr) * 32 + ((quad << 3) ^ sw)];
#pragma unroll
      for (int i = 0; i < 4; ++i)
#pragma unroll
        for (int j = 0; j < 4; ++j)
          acc[i][j] = __builtin_amdgcn_mfma_f32_16x16x32_f16(a[i], b[j], acc[i][j], 0, 0, 0);
    }
    __syncthreads();
  }

  // C/D layout: col = lane&15, row = (lane>>4)*4 + reg
  int col = lane & 15, rb = (lane >> 4) * 4;
  constexpr int D = 1 << dshift;
  constexpr int rstride = D << 1;
#pragma unroll
  for (int j = 0; j < 4; ++j) {
    int gc = n0 + wc * 64 + j * 16 + col;
    float bj = bias[gc];
    int mseg = gc >> dshift;
    int off = gc & (D - 1);
    bool toKV = (mseg == 1) || (mseg == 2);
    __half* base = toKV ? (KV + off + (mseg == 2 ? D : 0))
                        : (QS + off + (mseg == 3 ? D : 0));
#pragma unroll
    for (int i = 0; i < 4; ++i) {
#pragma unroll
      for (int r = 0; r < 4; ++r) {
        int gr = m0 + wr * 64 + i * 16 + rb + r;
        base[(size_t)gr * rstride] = __float2half(acc[i][j][r] + bj);
      }
    }
  }
}

// ---------------- attention H=8 C=64: one WAVE per node, 2-pair pipeline ----------------
__global__ __launch_bounds__(256)
void attn_h8_kernel(const __half* __restrict__ QS, const __half* __restrict__ KV,
                    const int* __restrict__ rowptr, const int* __restrict__ col,
                    __half* __restrict__ Hout, int N) {
  int n = blockIdx.x * 4 + (threadIdx.x >> 6);
  if (n >= N) return;
  int lane = threadIdx.x & 63;
  size_t rbase = (size_t)n * 1024 + lane * 8;

  f16x8 qv = __builtin_nontemporal_load((const f16x8*)(QS + rbase));
  float qf[8];
#pragma unroll
  for (int j = 0; j < 8; ++j) qf[j] = (float)qv[j];

  int e0 = rowptr[n], e1 = rowptr[n + 1];
  float m = -INFINITY, l = 0.f;
  float o[8] = {};

  f16x8 ka = {}, va = {}, kb = {}, vb = {};
  int i = e0;
  if (i < e1) {
    const __half* p = KV + (size_t)col[i] * 1024 + lane * 8;
    ka = *(const f16x8*)p; va = *(const f16x8*)(p + 512);
  }
  if (i + 1 < e1) {
    const __half* p = KV + (size_t)col[i + 1] * 1024 + lane * 8;
    kb = *(const f16x8*)p; vb = *(const f16x8*)(p + 512);
  }

  while (i < e1) {
    int rem = e1 - i;
    f16x8 kc = {}, vc = {}, kd = {}, vd = {};
    if (rem > 2) {
      const __half* p = KV + (size_t)col[i + 2] * 1024 + lane * 8;
      kc = *(const f16x8*)p; vc = *(const f16x8*)(p + 512);
    }
    if (rem > 3) {
      const __half* p = KV + (size_t)col[i + 3] * 1024 + lane * 8;
      kd = *(const f16x8*)p; vd = *(const f16x8*)(p + 512);
    }
    float pa = 0.f, pb = 0.f;
#pragma unroll
    for (int j = 0; j < 8; ++j) { pa += (float)ka[j] * qf[j]; pb += (float)kb[j] * qf[j]; }
    pa += __shfl_xor(pa, 1, 64); pb += __shfl_xor(pb, 1, 64);
    pa += __shfl_xor(pa, 2, 64); pb += __shfl_xor(pb, 2, 64);
    pa += __shfl_xor(pa, 4, 64); pb += __shfl_xor(pb, 4, 64);
    float a0 = pa * 0.125f;
    if (rem > 1) {
      float a1 = pb * 0.125f;
      float mn = fmaxf(m, fmaxf(a0, a1));
      float sc = __expf(m - mn);
      float ea = __expf(a0 - mn), eb = __expf(a1 - mn);
      l = l * sc + ea + eb;
#pragma unroll
      for (int c = 0; c < 8; ++c)
        o[c] = o[c] * sc + ea * (float)va[c] + eb * (float)vb[c];
      m = mn;
    } else {
      float mn = fmaxf(m, a0);
      float sc = __expf(m - mn);
      float ea = __expf(a0 - mn);
      l = l * sc + ea;
#pragma unroll
      for (int c = 0; c < 8; ++c) o[c] = o[c] * sc + ea * (float)va[c];
      m = mn;
    }
    ka = kc; va = vc; kb = kd; vb = vd;
    i += 2;
  }

  float inv = 1.f / (l + 1e-16f);
  f16x8 sv = __builtin_nontemporal_load((const f16x8*)(QS + rbase + 512));
  f16x8 hv;
#pragma unroll
  for (int c = 0; c < 8; ++c) {
    float r = o[c] * inv + (float)sv[c];
    hv[c] = (_Float16)fmaxf(r, 0.f);
  }
  __builtin_nontemporal_store(hv, (f16x8*)(Hout + (size_t)n * 512 + lane * 8));
}

// ---------------- attention H=1 C=64: 8-lane group per node, pipelined ----------------
__global__ __launch_bounds__(256)
void attn_h1_kernel(const __half* __restrict__ QS, const __half* __restrict__ KV,
                    const int* __restrict__ rowptr, const int* __restrict__ col,
                    float* __restrict__ out, int N) {
  int n = (blockIdx.x * 256 + threadIdx.x) >> 3;
  if (n >= N) return;
  int gl = threadIdx.x & 7;
  size_t rbase = (size_t)n * 128 + gl * 8;

  f16x8 qv = __builtin_nontemporal_load((const f16x8*)(QS + rbase));
  float qf[8];
#pragma unroll
  for (int j = 0; j < 8; ++j) qf[j] = (float)qv[j];

  int e0 = rowptr[n], e1 = rowptr[n + 1];
  float m = -INFINITY, l = 0.f;
  float o[8] = {};

  f16x8 ka = {}, va = {}, kb = {}, vb = {};
  int i = e0;
  if (i < e1) {
    const __half* p = KV + (size_t)col[i] * 128 + gl * 8;
    ka = *(const f16x8*)p; va = *(const f16x8*)(p + 64);
  }
  if (i + 1 < e1) {
    const __half* p = KV + (size_t)col[i + 1] * 128 + gl * 8;
    kb = *(const f16x8*)p; vb = *(const f16x8*)(p + 64);
  }

  while (i < e1) {
    int rem = e1 - i;
    f16x8 kc = {}, vc = {}, kd = {}, vd = {};
    if (rem > 2) {
      const __half* p = KV + (size_t)col[i + 2] * 128 + gl * 8;
      kc = *(const f16x8*)p; vc = *(const f16x8*)(p + 64);
    }
    if (rem > 3) {
      const __half* p = KV + (size_t)col[i + 3] * 128 + gl * 8;
      kd = *(const f16x8*)p; vd = *(const f16x8*)(p + 64);
    }
    float pa = 0.f, pb = 0.f;
#pragma unroll
    for (int j = 0; j < 8; ++j) { pa += (float)ka[j] * qf[j]; pb += (float)kb[j] * qf[j]; }
    pa += __shfl_xor(pa, 1, 64); pb += __shfl_xor(pb, 1, 64);
    pa += __shfl_xor(pa, 2, 64); pb += __shfl_xor(pb, 2, 64);
    pa += __shfl_xor(pa, 4, 64); pb += __shfl_xor(pb, 4, 64);
    float a0 = pa * 0.125f;
    if (rem > 1) {
      float a1 = pb * 0.125f;
      float mn = fmaxf(m, fmaxf(a0, a1));
      float sc = __expf(m - mn);
      float ea = __expf(a0 - mn), eb = __expf(a1 - mn);
      l = l * sc + ea + eb;
#pragma unroll
      for (int c = 0; c < 8; ++c)
        o[c] = o[c] * sc + ea * (float)va[c] + eb * (float)vb[c];
      m = mn;
    } else {
      float mn = fmaxf(m, a0);
      float sc = __expf(m - mn);
      float ea = __expf(a0 - mn);
      l = l * sc + ea;
#pragma unroll
      for (int c = 0; c < 8; ++c) o[c] = o[c] * sc + ea * (float)va[c];
      m = mn;
    }
    ka = kc; va = vc; kb = kd; vb = vd;
    i += 2;
  }

  float inv = 1.f / (l + 1e-16f);
  f16x8 sv = __builtin_nontemporal_load((const f16x8*)(QS + rbase + 64));
  f32x4 r0, r1;
#pragma unroll
  for (int c = 0; c < 4; ++c) r0[c] = o[c] * inv + (float)sv[c];
#pragma unroll
  for (int c = 0; c < 4; ++c) r1[c] = o[c + 4] * inv + (float)sv[c + 4];
  float* op = out + (size_t)n * 64 + gl * 8;
  *(f32x4*)op = r0;
  *(f32x4*)(op + 4) = r1;
}

extern "C" void kernel_launch(void* const* d_in, const int* in_sizes, int n_in,
                              void* d_out, int out_size, void* d_ws, size_t ws_size,
                              hipStream_t stream) {
  const float* x = (const float*)d_in[0];
  const int* ei = (const int*)d_in[1];
  const int N = in_sizes[0] / 128;
  const int E = in_sizes[1] / 2;
  const int Npad = ((N + 127) / 128) * 128;
  const int* srcp = ei;
  const int* dstp = ei + E;

  const float* Wq0 = (const float*)d_in[2];  const float* bq0 = (const float*)d_in[3];
  const float* Wk0 = (const float*)d_in[4];  const float* bk0 = (const float*)d_in[5];
  const float* Wv0 = (const float*)d_in[6];  const float* bv0 = (const float*)d_in[7];
  const float* Ws0 = (const float*)d_in[8];  const float* bs0 = (const float*)d_in[9];
  const float* Wq1 = (const float*)d_in[10]; const float* bq1 = (const float*)d_in[11];
  const float* Wk1 = (const float*)d_in[12]; const float* bk1 = (const float*)d_in[13];
  const float* Wv1 = (const float*)d_in[14]; const float* bv1 = (const float*)d_in[15];
  const float* Ws1 = (const float*)d_in[16]; const float* bs1 = (const float*)d_in[17];
  const float* Wq2 = (const float*)d_in[18]; const float* bq2 = (const float*)d_in[19];
  const float* Wk2 = (const float*)d_in[20]; const float* bk2 = (const float*)d_in[21];
  const float* Wv2 = (const float*)d_in[22]; const float* bv2 = (const float*)d_in[23];
  const float* Ws2 = (const float*)d_in[24]; const float* bs2 = (const float*)d_in[25];

  // ---- workspace layout (~260 MB) ----
  char* p = (char*)d_ws;
  __half* QS = (__half*)p;               p += (size_t)Npad * 1024 * 2;  // 102.5 MB
  __half* KV = (__half*)p;               p += (size_t)Npad * 1024 * 2;  // 102.5 MB
  __half* H  = (__half*)p;               p += (size_t)Npad * 512 * 2;   // 51.25 MB
  __half* Wt = (__half*)p;               p += (size_t)1441792 * 2;      // 2.88 MB
  float* bias_arena = (float*)p;         p += 4352 * 4;
  int* deg    = (int*)p;                 p += (size_t)N * 4;
  int* rowptr = (int*)p;                 p += (size_t)(N + 1) * 4;
  int* cursor = (int*)p;                 p += (size_t)(N + 1) * 4;
  int* colv   = (int*)p;                 p += (size_t)E * 4;
  int* bsum   = (int*)p;                 p += 256 * 4;
  size_t need = p - (char*)d_ws;
  if (ws_size < need) {
    fprintf(stderr, "kernel_launch: ws_size=%zu < need=%zu — aborting cleanly\n",
            ws_size, need);
    return;
  }

  const int nscan = (N + 255) / 256;  // 196 blocks (<=256 for scan_b)

  // ---- prep ----
  transpose_all_kernel<<<dim3(16, 16, 12), 256, 0, stream>>>(
      Wq0, Wk0, Wv0, Ws0, Wq1, Wk1, Wv1, Ws1, Wq2, Wk2, Wv2, Ws2, Wt);
  bias_all_kernel<<<12, 256, 0, stream>>>(
      bq0, bk0, bv0, bs0, bq1, bk1, bv1, bs1, bq2, bk2, bv2, bs2, bias_arena);
  zero_misc_kernel<<<(N + 255) / 256, 256, 0, stream>>>(deg, H, N, Npad);

  // ---- CSR build ----
  degree_kernel<<<(E + 255) / 256, 256, 0, stream>>>(dstp, deg, E);
  scan_a_kernel<<<nscan, 256, 0, stream>>>(deg, rowptr, bsum, N);
  scan_b_kernel<<<1, 256, 0, stream>>>(bsum, nscan);
  scan_c_kernel<<<nscan, 256, 0, stream>>>(rowptr, cursor, bsum, N);
  scatter_kernel<<<(E + 255) / 256, 256, 0, stream>>>(srcp, dstp, cursor, colv, E);

  const int mtiles = Npad / 128;
  __half* Wt0 = Wt;
  __half* Wt1 = Wt + 262144;
  __half* Wt2 = Wt + 1310720;

  // ---- layer 0: K=128, D=512 (reads fp32 x directly) ----
  gemm_mfma_kernel<0><<<dim3(16, mtiles), 256, 0, stream>>>(
      x, Wt0, bias_arena, QS, KV, N);
  attn_h8_kernel<<<(N + 3) / 4, 256, 0, stream>>>(QS, KV, rowptr, colv, H, N);

  // ---- layer 1: K=512, D=512 ----
  gemm_mfma_kernel<1><<<dim3(16, mtiles), 256, 0, stream>>>(
      H, Wt1, bias_arena + 2048, QS, KV, Npad);
  attn_h8_kernel<<<(N + 3) / 4, 256, 0, stream>>>(QS, KV, rowptr, colv, H, N);

  // ---- layer 2: K=512, D=64 ----
  gemm_mfma_kernel<2><<<dim3(2, mtiles), 256, 0, stream>>>(
      H, Wt2, bias_arena + 4096, QS, KV, Npad);
  attn_h1_kernel<<<(N + 31) / 32, 256, 0, stream>>>(QS, KV, rowptr, colv,
                                                    (float*)d_out, N);
}

// Round 11
// 979.571 us; speedup vs baseline: 1.1909x; 1.0514x over previous
//
#include <hip/hip_runtime.h>
#include <hip/hip_fp16.h>
#include <math.h>
#include <stdio.h>

// N=50000, E=800000, IN=128, C=64, H=8, H*C=512
// Round 11: GEMM rebuilt — 128x256 block tile, 64x128 wave tile (MFMA-bound:
// 12 ds_read_b128 vs 32 MFMA per 32-k), 128B LDS rows + XOR-8 slot swizzle,
// XCD-striped 1D grid (m-stripe per XCD -> A fetched once per XCD).
// Attention unchanged (pinned 240us/822MB across 4 variants = fabric floor).

using f16x8 = __attribute__((ext_vector_type(8))) _Float16;
using f32x4 = __attribute__((ext_vector_type(4))) float;

__device__ __forceinline__ void load_lds16(const void* g, void* l) {
  __builtin_amdgcn_global_load_lds((const __attribute__((address_space(1))) void*)g,
                                   (__attribute__((address_space(3))) void*)l,
                                   16, 0, 0);
}

// ---------------- CSR build ----------------
__global__ void zero_misc_kernel(int* __restrict__ deg, __half* __restrict__ H,
                                 int N, int Npad) {
  int t = blockIdx.x * 256 + threadIdx.x;
  if (t < N) deg[t] = 0;
  int nz = (Npad - N) * 512 / 8;
  if (t < nz) {
    f16x8 z = {};
    *(f16x8*)(H + (size_t)N * 512 + (size_t)t * 8) = z;
  }
}

__global__ void degree_kernel(const int* __restrict__ dst, int* __restrict__ deg, int E) {
  int e = blockIdx.x * blockDim.x + threadIdx.x;
  if (e < E) atomicAdd(&deg[dst[e]], 1);
}

__global__ __launch_bounds__(256)
void scan_a_kernel(const int* __restrict__ deg, int* __restrict__ rowptr,
                   int* __restrict__ bsum, int n) {
  __shared__ int tmp[256];
  int t = threadIdx.x;
  int i = blockIdx.x * 256 + t;
  int v = (i < n) ? deg[i] : 0;
  tmp[t] = v;
  __syncthreads();
#pragma unroll
  for (int off = 1; off < 256; off <<= 1) {
    int u = (t >= off) ? tmp[t - off] : 0;
    __syncthreads();
    tmp[t] += u;
    __syncthreads();
  }
  if (i < n) rowptr[i + 1] = tmp[t];
  if (t == 255) bsum[blockIdx.x] = tmp[255];
}

__global__ __launch_bounds__(256)
void scan_b_kernel(int* __restrict__ bsum, int nb) {
  __shared__ int tmp[256];
  int t = threadIdx.x;
  int v = (t < nb) ? bsum[t] : 0;
  tmp[t] = v;
  __syncthreads();
#pragma unroll
  for (int off = 1; off < 256; off <<= 1) {
    int u = (t >= off) ? tmp[t - off] : 0;
    __syncthreads();
    tmp[t] += u;
    __syncthreads();
  }
  if (t < nb) bsum[t] = tmp[t] - v;  // exclusive
}

__global__ __launch_bounds__(256)
void scan_c_kernel(int* __restrict__ rowptr, int* __restrict__ cursor,
                   const int* __restrict__ bsum, int n) {
  int i = blockIdx.x * 256 + threadIdx.x;
  if (i < n) {
    int r = rowptr[i + 1] + bsum[blockIdx.x];
    rowptr[i + 1] = r;
    cursor[i + 1] = r;
  }
  if (i == 0) { rowptr[0] = 0; cursor[0] = 0; }
}

__global__ void scatter_kernel(const int* __restrict__ src, const int* __restrict__ dst,
                               int* __restrict__ cursor, int* __restrict__ col, int E) {
  int e = blockIdx.x * blockDim.x + threadIdx.x;
  if (e < E) {
    int pos = atomicAdd(&cursor[dst[e]], 1);
    col[pos] = src[e];
  }
}

// ---------------- prep: weights/biases ----------------
__global__ __launch_bounds__(256)
void transpose_all_kernel(
    const float* __restrict__ Wq0, const float* __restrict__ Wk0,
    const float* __restrict__ Wv0, const float* __restrict__ Ws0,
    const float* __restrict__ Wq1, const float* __restrict__ Wk1,
    const float* __restrict__ Wv1, const float* __restrict__ Ws1,
    const float* __restrict__ Wq2, const float* __restrict__ Wk2,
    const float* __restrict__ Wv2, const float* __restrict__ Ws2,
    __half* __restrict__ Wt) {
  int z = blockIdx.z;
  int layer = z >> 2, m = z & 3;
  int K = (layer == 0) ? 128 : 512;
  int D = (layer == 2) ? 64 : 512;
  int c0 = blockIdx.x * 32, k0 = blockIdx.y * 32;
  if (c0 >= D || k0 >= K) return;
  const float* W;
  switch (z) {
    case 0: W = Wq0; break; case 1: W = Wk0; break;
    case 2: W = Wv0; break; case 3: W = Ws0; break;
    case 4: W = Wq1; break; case 5: W = Wk1; break;
    case 6: W = Wv1; break; case 7: W = Ws1; break;
    case 8: W = Wq2; break; case 9: W = Wk2; break;
    case 10: W = Wv2; break; default: W = Ws2; break;
  }
  __half* dstBase = Wt + ((layer == 0) ? 0 : (layer == 1) ? 262144 : 1310720);
  __shared__ float t[32][33];
  int tx = threadIdx.x & 31, ty = threadIdx.x >> 5;  // (32,8)
#pragma unroll
  for (int r = 0; r < 4; ++r)
    t[ty + 8 * r][tx] = W[(size_t)(k0 + ty + 8 * r) * D + c0 + tx];
  __syncthreads();
#pragma unroll
  for (int r = 0; r < 4; ++r)
    dstBase[(size_t)(m * D + c0 + ty + 8 * r) * K + k0 + tx] =
        __float2half(t[tx][ty + 8 * r]);
}

__global__ void bias_all_kernel(
    const float* __restrict__ b0, const float* __restrict__ b1,
    const float* __restrict__ b2, const float* __restrict__ b3,
    const float* __restrict__ b4, const float* __restrict__ b5,
    const float* __restrict__ b6, const float* __restrict__ b7,
    const float* __restrict__ b8, const float* __restrict__ b9,
    const float* __restrict__ b10, const float* __restrict__ b11,
    float* __restrict__ bias_arena) {
  int z = blockIdx.x;
  int layer = z >> 2, m = z & 3;
  int D = (layer == 2) ? 64 : 512;
  const float* b;
  switch (z) {
    case 0: b = b0; break; case 1: b = b1; break;
    case 2: b = b2; break; case 3: b = b3; break;
    case 4: b = b4; break; case 5: b = b5; break;
    case 6: b = b6; break; case 7: b = b7; break;
    case 8: b = b8; break; case 9: b = b9; break;
    case 10: b = b10; break; default: b = b11; break;
  }
  float* dst = bias_arena + ((layer == 0) ? 0 : (layer == 1) ? 2048 : 4096) + m * D;
  for (int c = threadIdx.x; c < D; c += 256) dst[c] = b[c];
}

// ---------------- MFMA GEMM: 128x256 block tile, 64x128 wave tile ----------------
// LDS rows = 64 halves (128B). Slot s (16B) of row r holds k-chunk s^(r&7).
// 1D grid, XCD-striped: xcd=bid&7; r=bid>>3; n=r%NT; m=(r/NT)*8+xcd.
// LAYER: 0 (A=fp32 x, K=128, D=512), 1 (A=H fp16, K=512, D=512),
//        2 (A=H fp16, K=512, D=64). mtiles must be divisible by 8.
template <int LAYER>
__global__ __launch_bounds__(256, 2)
void gemm_mfma_kernel(const void* __restrict__ Avoid,
                      const __half* __restrict__ Wt,
                      const float* __restrict__ bias,
                      __half* __restrict__ QS, __half* __restrict__ KV,
                      int Nrows) {
  constexpr int K = (LAYER == 0) ? 128 : 512;
  constexpr int dshift = (LAYER == 2) ? 6 : 9;
  constexpr int lda = (LAYER == 0) ? 128 : 512;
  constexpr int NT = (LAYER == 2) ? 1 : 8;  // 256-wide n-tiles
  __shared__ __align__(16) __half As[128 * 64];  // 16 KB
  __shared__ __align__(16) __half Bs[256 * 64];  // 32 KB
  int tid = threadIdx.x;
  int wave = tid >> 6, lane = tid & 63;
  int wr = wave >> 1, wc = wave & 1;
  int bid = blockIdx.x;
  int xcd = bid & 7;
  int r = bid >> 3;
  int n0 = (r % NT) * 256;
  int m0 = ((r / NT) * 8 + xcd) * 128;
  // staging decomposition: lane -> (row-in-8, slot)
  int srow = lane >> 3;
  int sslot = lane & 7;
  int skc = (sslot ^ srow) << 3;  // swizzled k offset (halves)
  // fragment read decomposition
  int quad = lane >> 4, rr = lane & 15;

  f32x4 acc[4][8] = {};

  for (int kt = 0; kt < K; kt += 64) {
    // stage A: wave covers rows [wave*32, +32): 4 calls x 8 rows
#pragma unroll
    for (int p = 0; p < 4; ++p) {
      int rbase = wave * 32 + p * 8;
      if constexpr (LAYER == 0) {
        int row = m0 + rbase + srow;
        const float* ga = (const float*)Avoid + (size_t)row * lda + kt + skc;
        f16x8 hv = {};
        if (row < Nrows) {
          float4 f0 = *(const float4*)ga;
          float4 f1 = *(const float4*)(ga + 4);
          hv[0] = (_Float16)f0.x; hv[1] = (_Float16)f0.y;
          hv[2] = (_Float16)f0.z; hv[3] = (_Float16)f0.w;
          hv[4] = (_Float16)f1.x; hv[5] = (_Float16)f1.y;
          hv[6] = (_Float16)f1.z; hv[7] = (_Float16)f1.w;
        }
        *(f16x8*)&As[(rbase + srow) * 64 + sslot * 8] = hv;
      } else {
        const __half* ga = (const __half*)Avoid +
                           (size_t)(m0 + rbase + srow) * lda + kt + skc;
        load_lds16(ga, &As[rbase * 64]);
      }
    }
    // stage B: wave covers rows [wave*64, +64): 8 calls x 8 rows
#pragma unroll
    for (int p = 0; p < 8; ++p) {
      int rbase = wave * 64 + p * 8;
      const __half* gb = Wt + (size_t)(n0 + rbase + srow) * K + kt + skc;
      load_lds16(gb, &Bs[rbase * 64]);
    }
    __syncthreads();
#pragma unroll
    for (int h = 0; h < 2; ++h) {
      int c = h * 4 + quad;  // k-chunk 0..7
      f16x8 a[4], b[8];
#pragma unroll
      for (int i = 0; i < 4; ++i) {
        int row = wr * 64 + i * 16 + rr;
        a[i] = *(const f16x8*)&As[row * 64 + ((c ^ (row & 7)) << 3)];
      }
#pragma unroll
      for (int j = 0; j < 8; ++j) {
        int row = wc * 128 + j * 16 + rr;
        b[j] = *(const f16x8*)&Bs[row * 64 + ((c ^ (row & 7)) << 3)];
      }
#pragma unroll
      for (int i = 0; i < 4; ++i)
#pragma unroll
        for (int j = 0; j < 8; ++j)
          acc[i][j] = __builtin_amdgcn_mfma_f32_16x16x32_f16(a[i], b[j], acc[i][j], 0, 0, 0);
    }
    __syncthreads();
  }

  // epilogue: C/D layout col = lane&15, row = (lane>>4)*4 + reg
  int col = lane & 15, rb = (lane >> 4) * 4;
  constexpr int D = 1 << dshift;
  constexpr int rstride = D << 1;
#pragma unroll
  for (int j = 0; j < 8; ++j) {
    int gc = n0 + wc * 128 + j * 16 + col;
    float bj = bias[gc];
    int mseg = gc >> dshift;
    int off = gc & (D - 1);
    bool toKV = (mseg == 1) || (mseg == 2);
    __half* base = toKV ? (KV + off + (mseg == 2 ? D : 0))
                        : (QS + off + (mseg == 3 ? D : 0));
#pragma unroll
    for (int i = 0; i < 4; ++i) {
#pragma unroll
      for (int rg = 0; rg < 4; ++rg) {
        int gr = m0 + wr * 64 + i * 16 + rb + rg;
        base[(size_t)gr * rstride] = __float2half(acc[i][j][rg] + bj);
      }
    }
  }
}

// ---------------- attention H=8 C=64: one WAVE per node, 2-pair pipeline ----------------
__global__ __launch_bounds__(256)
void attn_h8_kernel(const __half* __restrict__ QS, const __half* __restrict__ KV,
                    const int* __restrict__ rowptr, const int* __restrict__ col,
                    __half* __restrict__ Hout, int N) {
  int n = blockIdx.x * 4 + (threadIdx.x >> 6);
  if (n >= N) return;
  int lane = threadIdx.x & 63;
  size_t rbase = (size_t)n * 1024 + lane * 8;

  f16x8 qv = __builtin_nontemporal_load((const f16x8*)(QS + rbase));
  float qf[8];
#pragma unroll
  for (int j = 0; j < 8; ++j) qf[j] = (float)qv[j];

  int e0 = rowptr[n], e1 = rowptr[n + 1];
  float m = -INFINITY, l = 0.f;
  float o[8] = {};

  f16x8 ka = {}, va = {}, kb = {}, vb = {};
  int i = e0;
  if (i < e1) {
    const __half* p = KV + (size_t)col[i] * 1024 + lane * 8;
    ka = *(const f16x8*)p; va = *(const f16x8*)(p + 512);
  }
  if (i + 1 < e1) {
    const __half* p = KV + (size_t)col[i + 1] * 1024 + lane * 8;
    kb = *(const f16x8*)p; vb = *(const f16x8*)(p + 512);
  }

  while (i < e1) {
    int rem = e1 - i;
    f16x8 kc = {}, vc = {}, kd = {}, vd = {};
    if (rem > 2) {
      const __half* p = KV + (size_t)col[i + 2] * 1024 + lane * 8;
      kc = *(const f16x8*)p; vc = *(const f16x8*)(p + 512);
    }
    if (rem > 3) {
      const __half* p = KV + (size_t)col[i + 3] * 1024 + lane * 8;
      kd = *(const f16x8*)p; vd = *(const f16x8*)(p + 512);
    }
    float pa = 0.f, pb = 0.f;
#pragma unroll
    for (int j = 0; j < 8; ++j) { pa += (float)ka[j] * qf[j]; pb += (float)kb[j] * qf[j]; }
    pa += __shfl_xor(pa, 1, 64); pb += __shfl_xor(pb, 1, 64);
    pa += __shfl_xor(pa, 2, 64); pb += __shfl_xor(pb, 2, 64);
    pa += __shfl_xor(pa, 4, 64); pb += __shfl_xor(pb, 4, 64);
    float a0 = pa * 0.125f;
    if (rem > 1) {
      float a1 = pb * 0.125f;
      float mn = fmaxf(m, fmaxf(a0, a1));
      float sc = __expf(m - mn);
      float ea = __expf(a0 - mn), eb = __expf(a1 - mn);
      l = l * sc + ea + eb;
#pragma unroll
      for (int c = 0; c < 8; ++c)
        o[c] = o[c] * sc + ea * (float)va[c] + eb * (float)vb[c];
      m = mn;
    } else {
      float mn = fmaxf(m, a0);
      float sc = __expf(m - mn);
      float ea = __expf(a0 - mn);
      l = l * sc + ea;
#pragma unroll
      for (int c = 0; c < 8; ++c) o[c] = o[c] * sc + ea * (float)va[c];
      m = mn;
    }
    ka = kc; va = vc; kb = kd; vb = vd;
    i += 2;
  }

  float inv = 1.f / (l + 1e-16f);
  f16x8 sv = __builtin_nontemporal_load((const f16x8*)(QS + rbase + 512));
  f16x8 hv;
#pragma unroll
  for (int c = 0; c < 8; ++c) {
    float r = o[c] * inv + (float)sv[c];
    hv[c] = (_Float16)fmaxf(r, 0.f);
  }
  __builtin_nontemporal_store(hv, (f16x8*)(Hout + (size_t)n * 512 + lane * 8));
}

// ---------------- attention H=1 C=64: 8-lane group per node, pipelined ----------------
__global__ __launch_bounds__(256)
void attn_h1_kernel(const __half* __restrict__ QS, const __half* __restrict__ KV,
                    const int* __restrict__ rowptr, const int* __restrict__ col,
                    float* __restrict__ out, int N) {
  int n = (blockIdx.x * 256 + threadIdx.x) >> 3;
  if (n >= N) return;
  int gl = threadIdx.x & 7;
  size_t rbase = (size_t)n * 128 + gl * 8;

  f16x8 qv = __builtin_nontemporal_load((const f16x8*)(QS + rbase));
  float qf[8];
#pragma unroll
  for (int j = 0; j < 8; ++j) qf[j] = (float)qv[j];

  int e0 = rowptr[n], e1 = rowptr[n + 1];
  float m = -INFINITY, l = 0.f;
  float o[8] = {};

  f16x8 ka = {}, va = {}, kb = {}, vb = {};
  int i = e0;
  if (i < e1) {
    const __half* p = KV + (size_t)col[i] * 128 + gl * 8;
    ka = *(const f16x8*)p; va = *(const f16x8*)(p + 64);
  }
  if (i + 1 < e1) {
    const __half* p = KV + (size_t)col[i + 1] * 128 + gl * 8;
    kb = *(const f16x8*)p; vb = *(const f16x8*)(p + 64);
  }

  while (i < e1) {
    int rem = e1 - i;
    f16x8 kc = {}, vc = {}, kd = {}, vd = {};
    if (rem > 2) {
      const __half* p = KV + (size_t)col[i + 2] * 128 + gl * 8;
      kc = *(const f16x8*)p; vc = *(const f16x8*)(p + 64);
    }
    if (rem > 3) {
      const __half* p = KV + (size_t)col[i + 3] * 128 + gl * 8;
      kd = *(const f16x8*)p; vd = *(const f16x8*)(p + 64);
    }
    float pa = 0.f, pb = 0.f;
#pragma unroll
    for (int j = 0; j < 8; ++j) { pa += (float)ka[j] * qf[j]; pb += (float)kb[j] * qf[j]; }
    pa += __shfl_xor(pa, 1, 64); pb += __shfl_xor(pb, 1, 64);
    pa += __shfl_xor(pa, 2, 64); pb += __shfl_xor(pb, 2, 64);
    pa += __shfl_xor(pa, 4, 64); pb += __shfl_xor(pb, 4, 64);
    float a0 = pa * 0.125f;
    if (rem > 1) {
      float a1 = pb * 0.125f;
      float mn = fmaxf(m, fmaxf(a0, a1));
      float sc = __expf(m - mn);
      float ea = __expf(a0 - mn), eb = __expf(a1 - mn);
      l = l * sc + ea + eb;
#pragma unroll
      for (int c = 0; c < 8; ++c)
        o[c] = o[c] * sc + ea * (float)va[c] + eb * (float)vb[c];
      m = mn;
    } else {
      float mn = fmaxf(m, a0);
      float sc = __expf(m - mn);
      float ea = __expf(a0 - mn);
      l = l * sc + ea;
#pragma unroll
      for (int c = 0; c < 8; ++c) o[c] = o[c] * sc + ea * (float)va[c];
      m = mn;
    }
    ka = kc; va = vc; kb = kd; vb = vd;
    i += 2;
  }

  float inv = 1.f / (l + 1e-16f);
  f16x8 sv = __builtin_nontemporal_load((const f16x8*)(QS + rbase + 64));
  f32x4 r0, r1;
#pragma unroll
  for (int c = 0; c < 4; ++c) r0[c] = o[c] * inv + (float)sv[c];
#pragma unroll
  for (int c = 0; c < 4; ++c) r1[c] = o[c + 4] * inv + (float)sv[c + 4];
  float* op = out + (size_t)n * 64 + gl * 8;
  *(f32x4*)op = r0;
  *(f32x4*)(op + 4) = r1;
}

extern "C" void kernel_launch(void* const* d_in, const int* in_sizes, int n_in,
                              void* d_out, int out_size, void* d_ws, size_t ws_size,
                              hipStream_t stream) {
  const float* x = (const float*)d_in[0];
  const int* ei = (const int*)d_in[1];
  const int N = in_sizes[0] / 128;
  const int E = in_sizes[1] / 2;
  // pad M so mtiles is a multiple of 8 (XCD striping)
  const int Npad = ((N + 1023) / 1024) * 1024;
  const int mtiles = Npad / 128;
  const int* srcp = ei;
  const int* dstp = ei + E;

  const float* Wq0 = (const float*)d_in[2];  const float* bq0 = (const float*)d_in[3];
  const float* Wk0 = (const float*)d_in[4];  const float* bk0 = (const float*)d_in[5];
  const float* Wv0 = (const float*)d_in[6];  const float* bv0 = (const float*)d_in[7];
  const float* Ws0 = (const float*)d_in[8];  const float* bs0 = (const float*)d_in[9];
  const float* Wq1 = (const float*)d_in[10]; const float* bq1 = (const float*)d_in[11];
  const float* Wk1 = (const float*)d_in[12]; const float* bk1 = (const float*)d_in[13];
  const float* Wv1 = (const float*)d_in[14]; const float* bv1 = (const float*)d_in[15];
  const float* Ws1 = (const float*)d_in[16]; const float* bs1 = (const float*)d_in[17];
  const float* Wq2 = (const float*)d_in[18]; const float* bq2 = (const float*)d_in[19];
  const float* Wk2 = (const float*)d_in[20]; const float* bk2 = (const float*)d_in[21];
  const float* Wv2 = (const float*)d_in[22]; const float* bv2 = (const float*)d_in[23];
  const float* Ws2 = (const float*)d_in[24]; const float* bs2 = (const float*)d_in[25];

  // ---- workspace layout (~260 MB) ----
  char* p = (char*)d_ws;
  __half* QS = (__half*)p;               p += (size_t)Npad * 1024 * 2;  // 102.8 MB
  __half* KV = (__half*)p;               p += (size_t)Npad * 1024 * 2;  // 102.8 MB
  __half* H  = (__half*)p;               p += (size_t)Npad * 512 * 2;   // 51.4 MB
  __half* Wt = (__half*)p;               p += (size_t)1441792 * 2;      // 2.88 MB
  float* bias_arena = (float*)p;         p += 4352 * 4;
  int* deg    = (int*)p;                 p += (size_t)N * 4;
  int* rowptr = (int*)p;                 p += (size_t)(N + 1) * 4;
  int* cursor = (int*)p;                 p += (size_t)(N + 1) * 4;
  int* colv   = (int*)p;                 p += (size_t)E * 4;
  int* bsum   = (int*)p;                 p += 256 * 4;
  size_t need = p - (char*)d_ws;
  if (ws_size < need) {
    fprintf(stderr, "kernel_launch: ws_size=%zu < need=%zu — aborting cleanly\n",
            ws_size, need);
    return;
  }

  const int nscan = (N + 255) / 256;

  // ---- prep ----
  transpose_all_kernel<<<dim3(16, 16, 12), 256, 0, stream>>>(
      Wq0, Wk0, Wv0, Ws0, Wq1, Wk1, Wv1, Ws1, Wq2, Wk2, Wv2, Ws2, Wt);
  bias_all_kernel<<<12, 256, 0, stream>>>(
      bq0, bk0, bv0, bs0, bq1, bk1, bv1, bs1, bq2, bk2, bv2, bs2, bias_arena);
  zero_misc_kernel<<<((Npad - N) * 512 / 8 + 255) / 256 > (N + 255) / 256
                         ? ((Npad - N) * 512 / 8 + 255) / 256
                         : (N + 255) / 256,
                    256, 0, stream>>>(deg, H, N, Npad);

  // ---- CSR build ----
  degree_kernel<<<(E + 255) / 256, 256, 0, stream>>>(dstp, deg, E);
  scan_a_kernel<<<nscan, 256, 0, stream>>>(deg, rowptr, bsum, N);
  scan_b_kernel<<<1, 256, 0, stream>>>(bsum, nscan);
  scan_c_kernel<<<nscan, 256, 0, stream>>>(rowptr, cursor, bsum, N);
  scatter_kernel<<<(E + 255) / 256, 256, 0, stream>>>(srcp, dstp, cursor, colv, E);

  __half* Wt0 = Wt;
  __half* Wt1 = Wt + 262144;
  __half* Wt2 = Wt + 1310720;

  // ---- layer 0: K=128, D=512, n-tiles 8 ----
  gemm_mfma_kernel<0><<<mtiles * 8, 256, 0, stream>>>(
      x, Wt0, bias_arena, QS, KV, N);
  attn_h8_kernel<<<(N + 3) / 4, 256, 0, stream>>>(QS, KV, rowptr, colv, H, N);

  // ---- layer 1: K=512, D=512, n-tiles 8 ----
  gemm_mfma_kernel<1><<<mtiles * 8, 256, 0, stream>>>(
      H, Wt1, bias_arena + 2048, QS, KV, Npad);
  attn_h8_kernel<<<(N + 3) / 4, 256, 0, stream>>>(QS, KV, rowptr, colv, H, N);

  // ---- layer 2: K=512, D=64, n-tiles 1 ----
  gemm_mfma_kernel<2><<<mtiles, 256, 0, stream>>>(
      H, Wt2, bias_arena + 4096, QS, KV, Npad);
  attn_h1_kernel<<<(N + 31) / 32, 256, 0, stream>>>(QS, KV, rowptr, colv,
                                                    (float*)d_out, N);
}